// Round 1
// baseline (1604.402 us; speedup 1.0000x reference)
//
#include <hip/hip_runtime.h>
#include <math.h>

#define N_TOT 32768
#define BB 64
#define LL 512
#define NNBR 15
#define EDGEF 29

// ---------------------------------------------------------------- frames
__global__ __launch_bounds__(256) void k_frames(const float* __restrict__ tert,
                                                float* __restrict__ pos,
                                                float* __restrict__ R) {
  int n = blockIdx.x * 256 + threadIdx.x;
  if (n >= N_TOT) return;
  float px = tert[n * 9 + 3], py = tert[n * 9 + 4], pz = tert[n * 9 + 5];
  pos[n * 3 + 0] = px; pos[n * 3 + 1] = py; pos[n * 3 + 2] = pz;

  int i0 = (n > 0) ? (n - 1) : 0;          // up = u[i0]
  int i1 = (n < N_TOT - 1) ? n : (N_TOT - 2);  // un = u[i1]

  float ax = tert[(i0 + 1) * 9 + 3] - tert[i0 * 9 + 3];
  float ay = tert[(i0 + 1) * 9 + 4] - tert[i0 * 9 + 4];
  float az = tert[(i0 + 1) * 9 + 5] - tert[i0 * 9 + 5];
  float il = 1.f / (sqrtf(ax * ax + ay * ay + az * az) + 1e-8f);
  float ux = ax * il, uy = ay * il, uz = az * il;

  float cx = tert[(i1 + 1) * 9 + 3] - tert[i1 * 9 + 3];
  float cy = tert[(i1 + 1) * 9 + 4] - tert[i1 * 9 + 4];
  float cz = tert[(i1 + 1) * 9 + 5] - tert[i1 * 9 + 5];
  il = 1.f / (sqrtf(cx * cx + cy * cy + cz * cz) + 1e-8f);
  float vx = cx * il, vy = cy * il, vz = cz * il;

  float bx = ux - vx, by = uy - vy, bz = uz - vz;
  il = 1.f / (sqrtf(bx * bx + by * by + bz * bz) + 1e-8f);
  bx *= il; by *= il; bz *= il;

  float nx = uy * vz - uz * vy;
  float ny = uz * vx - ux * vz;
  float nz = ux * vy - uy * vx;
  il = 1.f / (sqrtf(nx * nx + ny * ny + nz * nz) + 1e-8f);
  nx *= il; ny *= il; nz *= il;

  float ex = by * nz - bz * ny;
  float ey = bz * nx - bx * nz;
  float ez = bx * ny - by * nx;

  float* Rn = R + (size_t)n * 9;
  Rn[0] = bx; Rn[1] = nx; Rn[2] = ex;
  Rn[3] = by; Rn[4] = ny; Rn[5] = ey;
  Rn[6] = bz; Rn[7] = nz; Rn[8] = ez;
}

// ---------------------------------------------------------------- kNN
// one wave per (b,i) row; iterative argmax x15 with lowest-index tie-break
__global__ __launch_bounds__(256) void k_knn(const float* __restrict__ pos,
                                             const float* __restrict__ noise,
                                             int* __restrict__ nbr) {
  int wave = threadIdx.x >> 6, lane = threadIdx.x & 63;
  int row = blockIdx.x * 4 + wave;  // = b*512 + i
  int b = row >> 9;
  float pix = pos[row * 3 + 0], piy = pos[row * 3 + 1], piz = pos[row * 3 + 2];
  float c[8];
  const float* nrow = noise + (size_t)row * 512;
#pragma unroll
  for (int jj = 0; jj < 8; jj++) {
    int j = lane + jj * 64;
    int g = b * 512 + j;
    float dx = pos[g * 3 + 0] - pix;
    float dy = pos[g * 3 + 1] - piy;
    float dz = pos[g * 3 + 2] - piz;
    float dist = sqrtf(dx * dx + dy * dy + dz * dz);
    c[jj] = -dist + 3.f * nrow[j];
  }
  int* outp = nbr + (size_t)row * NNBR;
  for (int it = 0; it < NNBR; it++) {
    float bv = -INFINITY; int bj = 1 << 30;
#pragma unroll
    for (int jj = 0; jj < 8; jj++) {
      int j = lane + jj * 64;
      if (c[jj] > bv || (c[jj] == bv && j < bj)) { bv = c[jj]; bj = j; }
    }
#pragma unroll
    for (int m = 1; m < 64; m <<= 1) {
      float ov = __shfl_xor(bv, m);
      int oj = __shfl_xor(bj, m);
      if (ov > bv || (ov == bv && oj < bj)) { bv = ov; bj = oj; }
    }
    if (lane == (bj & 63)) c[bj >> 6] = -INFINITY;
    if (lane == 0) outp[it] = b * 512 + bj;
  }
}

// ---------------------------------------------------------------- edge features
__global__ __launch_bounds__(256) void k_edge(const float* __restrict__ pos,
                                              const float* __restrict__ R,
                                              const int* __restrict__ nbr,
                                              float* __restrict__ edge) {
  int idx = blockIdx.x * 256 + threadIdx.x;
  if (idx >= N_TOT * NNBR) return;
  int n = idx / NNBR;
  int m = nbr[idx];
  float dx = pos[m * 3 + 0] - pos[n * 3 + 0];
  float dy = pos[m * 3 + 1] - pos[n * 3 + 1];
  float dz = pos[m * 3 + 2] - pos[n * 3 + 2];
  float d = sqrtf(dx * dx + dy * dy + dz * dz);
  float* e = edge + (size_t)idx * EDGEF;
#pragma unroll
  for (int j = 0; j < 16; j++) {
    float mu = (20.f / 15.f) * (float)j;
    float t = (d - mu) * 0.8f;  // /1.25
    e[j] = __expf(-t * t);
  }
  float inv = 1.f / (d + 1e-8f);
  float ux = dx * inv, uy = dy * inv, uz = dz * inv;
  float Rn[9], Rm[9];
#pragma unroll
  for (int j = 0; j < 9; j++) { Rn[j] = R[(size_t)n * 9 + j]; Rm[j] = R[(size_t)m * 9 + j]; }
#pragma unroll
  for (int cc = 0; cc < 3; cc++)
    e[16 + cc] = Rn[0 * 3 + cc] * ux + Rn[1 * 3 + cc] * uy + Rn[2 * 3 + cc] * uz;
#pragma unroll
  for (int cc = 0; cc < 3; cc++)
#pragma unroll
    for (int dd = 0; dd < 3; dd++)
      e[19 + cc * 3 + dd] = Rn[0 * 3 + cc] * Rm[0 * 3 + dd] +
                            Rn[1 * 3 + cc] * Rm[1 * 3 + dd] +
                            Rn[2 * 3 + cc] * Rm[2 * 3 + dd];
  e[28] = (float)(m - n);
}

// ---------------------------------------------------------------- h init
__global__ __launch_bounds__(256) void k_hinit(const float* __restrict__ ew,
                                               const float* __restrict__ ebias,
                                               float* __restrict__ h) {
  __shared__ float hv[128];
  int tid = threadIdx.x;
  if (tid < 128) {
    float s = ebias[tid];
#pragma unroll
    for (int i = 0; i < 27; i++) s += ew[i * 128 + tid];
    hv[tid] = s;
  }
  __syncthreads();
  size_t total = (size_t)N_TOT * 128;
  for (size_t j = (size_t)blockIdx.x * 256 + tid; j < total; j += (size_t)gridDim.x * 256)
    h[j] = hv[j & 127];
}

// ---------------------------------------------------------------- generic GEMM: C = act(A@W [+bias]) [+res]
__global__ __launch_bounds__(256) void k_gemm(const float* __restrict__ A,
                                              const float* __restrict__ W,
                                              const float* __restrict__ bias,
                                              const float* __restrict__ res,
                                              float* __restrict__ C, int relu) {
  __shared__ float At[64][128];
  int r0 = blockIdx.x * 64, tid = threadIdx.x;
  const float4* A4 = (const float4*)(A + (size_t)r0 * 128);
  float4* At4 = (float4*)(&At[0][0]);
  for (int j = tid; j < 2048; j += 256) At4[j] = A4[j];
  __syncthreads();
  int c4 = (tid & 31) * 4, rg = (tid >> 5) * 8;
  float acc[8][4];
#pragma unroll
  for (int r = 0; r < 8; r++)
#pragma unroll
    for (int cc = 0; cc < 4; cc++) acc[r][cc] = 0.f;
  for (int k = 0; k < 128; k++) {
    float4 w = *(const float4*)(W + k * 128 + c4);
#pragma unroll
    for (int r = 0; r < 8; r++) {
      float a = At[rg + r][k];
      acc[r][0] = fmaf(a, w.x, acc[r][0]);
      acc[r][1] = fmaf(a, w.y, acc[r][1]);
      acc[r][2] = fmaf(a, w.z, acc[r][2]);
      acc[r][3] = fmaf(a, w.w, acc[r][3]);
    }
  }
  float4 bv = make_float4(0.f, 0.f, 0.f, 0.f);
  if (bias) bv = *(const float4*)(bias + c4);
#pragma unroll
  for (int r = 0; r < 8; r++) {
    size_t o = ((size_t)(r0 + rg + r)) * 128 + c4;
    float4 v;
    v.x = acc[r][0] + bv.x; v.y = acc[r][1] + bv.y;
    v.z = acc[r][2] + bv.z; v.w = acc[r][3] + bv.w;
    if (relu) { v.x = fmaxf(v.x, 0.f); v.y = fmaxf(v.y, 0.f); v.z = fmaxf(v.z, 0.f); v.w = fmaxf(v.w, 0.f); }
    if (res) {
      float4 rr = *(const float4*)(res + o);
      v.x += rr.x; v.y += rr.y; v.z += rr.z; v.w += rr.w;
    }
    *(float4*)(C + o) = v;
  }
}

// ---------------------------------------------------------------- fused 3-output GEMM (q, hk, hv)
__global__ __launch_bounds__(256) void k_gemm3(const float* __restrict__ A,
                                               const float* __restrict__ W0,
                                               const float* __restrict__ W1,
                                               const float* __restrict__ W2,
                                               float* __restrict__ C0,
                                               float* __restrict__ C1,
                                               float* __restrict__ C2) {
  __shared__ float At[64][128];
  int r0 = blockIdx.x * 64, tid = threadIdx.x;
  const float4* A4 = (const float4*)(A + (size_t)r0 * 128);
  float4* At4 = (float4*)(&At[0][0]);
  for (int j = tid; j < 2048; j += 256) At4[j] = A4[j];
  __syncthreads();
  int c4 = (tid & 31) * 4, rg = (tid >> 5) * 8;
  float a0[8][4], a1[8][4], a2[8][4];
#pragma unroll
  for (int r = 0; r < 8; r++)
#pragma unroll
    for (int cc = 0; cc < 4; cc++) { a0[r][cc] = 0.f; a1[r][cc] = 0.f; a2[r][cc] = 0.f; }
  for (int k = 0; k < 128; k++) {
    float4 w0 = *(const float4*)(W0 + k * 128 + c4);
    float4 w1 = *(const float4*)(W1 + k * 128 + c4);
    float4 w2 = *(const float4*)(W2 + k * 128 + c4);
#pragma unroll
    for (int r = 0; r < 8; r++) {
      float a = At[rg + r][k];
      a0[r][0] = fmaf(a, w0.x, a0[r][0]); a0[r][1] = fmaf(a, w0.y, a0[r][1]);
      a0[r][2] = fmaf(a, w0.z, a0[r][2]); a0[r][3] = fmaf(a, w0.w, a0[r][3]);
      a1[r][0] = fmaf(a, w1.x, a1[r][0]); a1[r][1] = fmaf(a, w1.y, a1[r][1]);
      a1[r][2] = fmaf(a, w1.z, a1[r][2]); a1[r][3] = fmaf(a, w1.w, a1[r][3]);
      a2[r][0] = fmaf(a, w2.x, a2[r][0]); a2[r][1] = fmaf(a, w2.y, a2[r][1]);
      a2[r][2] = fmaf(a, w2.z, a2[r][2]); a2[r][3] = fmaf(a, w2.w, a2[r][3]);
    }
  }
#pragma unroll
  for (int r = 0; r < 8; r++) {
    size_t o = ((size_t)(r0 + rg + r)) * 128 + c4;
    *(float4*)(C0 + o) = make_float4(a0[r][0], a0[r][1], a0[r][2], a0[r][3]);
    *(float4*)(C1 + o) = make_float4(a1[r][0], a1[r][1], a1[r][2], a1[r][3]);
    *(float4*)(C2 + o) = make_float4(a2[r][0], a2[r][1], a2[r][2], a2[r][3]);
  }
}

// ---------------------------------------------------------------- fused attention (online softmax, edge-proj in regs)
#define NPW 8
__global__ __launch_bounds__(256) void k_attn(const float* __restrict__ q,
                                              const float* __restrict__ hk,
                                              const float* __restrict__ hv,
                                              const int* __restrict__ nbr,
                                              const float* __restrict__ edge,
                                              const float* __restrict__ wkb,
                                              const float* __restrict__ wvb,
                                              float* __restrict__ o) {
  __shared__ float elds[4][NNBR * EDGEF + 1];
  int wave = threadIdx.x >> 6, lane = threadIdx.x & 63;
  int c2 = lane * 2;
  float2 wkr[EDGEF], wvr[EDGEF];
#pragma unroll
  for (int e = 0; e < EDGEF; e++) {
    wkr[e] = *(const float2*)(wkb + e * 128 + c2);
    wvr[e] = *(const float2*)(wvb + e * 128 + c2);
  }
  int nbase = (blockIdx.x * 4 + wave) * NPW;
  for (int ni = 0; ni < NPW; ni++) {
    int n = nbase + ni;
    for (int j = lane; j < NNBR * EDGEF; j += 64)
      elds[wave][j] = edge[(size_t)n * (NNBR * EDGEF) + j];
    __syncthreads();
    float2 q2 = *(const float2*)(q + (size_t)n * 128 + c2);
    q2.x *= 0.25f; q2.y *= 0.25f;  // 1/sqrt(AH)
    float mrun = -INFINITY, lrun = 0.f;
    float ox = 0.f, oy = 0.f;
    const int* nb = nbr + (size_t)n * NNBR;
#pragma unroll 1
    for (int k = 0; k < NNBR; k++) {
      int m = nb[k];
      float2 kk = *(const float2*)(hk + (size_t)m * 128 + c2);
      float2 vv = *(const float2*)(hv + (size_t)m * 128 + c2);
      const float* ep = &elds[wave][k * EDGEF];
#pragma unroll
      for (int e = 0; e < EDGEF; e++) {
        float ee = ep[e];
        kk.x = fmaf(ee, wkr[e].x, kk.x); kk.y = fmaf(ee, wkr[e].y, kk.y);
        vv.x = fmaf(ee, wvr[e].x, vv.x); vv.y = fmaf(ee, wvr[e].y, vv.y);
      }
      float part = q2.x * kk.x + q2.y * kk.y;
      part += __shfl_xor(part, 1);
      part += __shfl_xor(part, 2);
      part += __shfl_xor(part, 4);  // logit for this head, all 8 lanes
      float mnew = fmaxf(mrun, part);
      float sc = __expf(mrun - mnew);
      float p = __expf(part - mnew);
      ox = ox * sc + p * vv.x;
      oy = oy * sc + p * vv.y;
      lrun = lrun * sc + p;
      mrun = mnew;
    }
    float inv = 1.f / lrun;
    *(float2*)(o + (size_t)n * 128 + c2) = make_float2(ox * inv, oy * inv);
    __syncthreads();
  }
}

// ---------------------------------------------------------------- fused MLP: h += W3(relu(W2(relu(W1 h + b1)) + b2)) + b3
__global__ __launch_bounds__(256) void k_mlp(float* __restrict__ h,
                                             const float* __restrict__ W1, const float* __restrict__ B1,
                                             const float* __restrict__ W2, const float* __restrict__ B2,
                                             const float* __restrict__ W3, const float* __restrict__ B3) {
  __shared__ float Ta[64][128];
  __shared__ float Tb[64][128];
  int r0 = blockIdx.x * 64, tid = threadIdx.x;
  const float4* A4 = (const float4*)(h + (size_t)r0 * 128);
  float4* Ta4 = (float4*)(&Ta[0][0]);
  for (int j = tid; j < 2048; j += 256) Ta4[j] = A4[j];
  __syncthreads();
  int c4 = (tid & 31) * 4, rg = (tid >> 5) * 8;
  float acc[8][4];

  // stage 1: Tb = relu(Ta@W1 + b1)
  {
    float4 bv = *(const float4*)(B1 + c4);
#pragma unroll
    for (int r = 0; r < 8; r++) { acc[r][0] = bv.x; acc[r][1] = bv.y; acc[r][2] = bv.z; acc[r][3] = bv.w; }
    for (int k = 0; k < 128; k++) {
      float4 w = *(const float4*)(W1 + k * 128 + c4);
#pragma unroll
      for (int r = 0; r < 8; r++) {
        float a = Ta[rg + r][k];
        acc[r][0] = fmaf(a, w.x, acc[r][0]); acc[r][1] = fmaf(a, w.y, acc[r][1]);
        acc[r][2] = fmaf(a, w.z, acc[r][2]); acc[r][3] = fmaf(a, w.w, acc[r][3]);
      }
    }
#pragma unroll
    for (int r = 0; r < 8; r++)
      *(float4*)(&Tb[rg + r][c4]) = make_float4(fmaxf(acc[r][0], 0.f), fmaxf(acc[r][1], 0.f),
                                                fmaxf(acc[r][2], 0.f), fmaxf(acc[r][3], 0.f));
    __syncthreads();
  }
  // stage 2: Ta = relu(Tb@W2 + b2)
  {
    float4 bv = *(const float4*)(B2 + c4);
#pragma unroll
    for (int r = 0; r < 8; r++) { acc[r][0] = bv.x; acc[r][1] = bv.y; acc[r][2] = bv.z; acc[r][3] = bv.w; }
    for (int k = 0; k < 128; k++) {
      float4 w = *(const float4*)(W2 + k * 128 + c4);
#pragma unroll
      for (int r = 0; r < 8; r++) {
        float a = Tb[rg + r][k];
        acc[r][0] = fmaf(a, w.x, acc[r][0]); acc[r][1] = fmaf(a, w.y, acc[r][1]);
        acc[r][2] = fmaf(a, w.z, acc[r][2]); acc[r][3] = fmaf(a, w.w, acc[r][3]);
      }
    }
    __syncthreads();  // everyone done reading Ta (stage1) & Tb; safe to overwrite Ta
#pragma unroll
    for (int r = 0; r < 8; r++)
      *(float4*)(&Ta[rg + r][c4]) = make_float4(fmaxf(acc[r][0], 0.f), fmaxf(acc[r][1], 0.f),
                                                fmaxf(acc[r][2], 0.f), fmaxf(acc[r][3], 0.f));
    __syncthreads();
  }
  // stage 3: h += Ta@W3 + b3
  {
    float4 bv = *(const float4*)(B3 + c4);
#pragma unroll
    for (int r = 0; r < 8; r++) { acc[r][0] = bv.x; acc[r][1] = bv.y; acc[r][2] = bv.z; acc[r][3] = bv.w; }
    for (int k = 0; k < 128; k++) {
      float4 w = *(const float4*)(W3 + k * 128 + c4);
#pragma unroll
      for (int r = 0; r < 8; r++) {
        float a = Ta[rg + r][k];
        acc[r][0] = fmaf(a, w.x, acc[r][0]); acc[r][1] = fmaf(a, w.y, acc[r][1]);
        acc[r][2] = fmaf(a, w.z, acc[r][2]); acc[r][3] = fmaf(a, w.w, acc[r][3]);
      }
    }
#pragma unroll
    for (int r = 0; r < 8; r++) {
      size_t oo = ((size_t)(r0 + rg + r)) * 128 + c4;
      float4 hh = *(const float4*)(h + oo);
      *(float4*)(h + oo) = make_float4(hh.x + acc[r][0], hh.y + acc[r][1],
                                       hh.z + acc[r][2], hh.w + acc[r][3]);
    }
  }
}

// ---------------------------------------------------------------- pool-weight transpose (s,o,i,kt) -> (s,kt,i,o)
__global__ __launch_bounds__(256) void k_transw(const float* __restrict__ pw, float* __restrict__ wt) {
  int idx = blockIdx.x * 256 + threadIdx.x;
  if (idx >= 4 * 128 * 128 * 3) return;
  int kt = idx % 3;
  int rest = idx / 3;
  int i = rest % 128; rest /= 128;
  int oo = rest % 128;
  int s = rest / 128;
  wt[(((size_t)s * 3 + kt) * 128 + i) * 128 + oo] = pw[idx];
}

// ---------------------------------------------------------------- conv(k=3,pad=1) + bias + leaky + residual + maxpool2
// in/out layout: (B, T, 128) with channel contiguous
__global__ __launch_bounds__(256) void k_convpool(const float* __restrict__ x,
                                                  const float* __restrict__ wt,
                                                  const float* __restrict__ bias,
                                                  float* __restrict__ outp, int Tin) {
  __shared__ float xt[128][67];
  int b = blockIdx.y;
  int t0 = blockIdx.x * 64;
  int tid = threadIdx.x;
  for (int j = tid; j < 128 * 66; j += 256) {
    int tl = j >> 7, i = j & 127;
    int t = t0 - 1 + tl;
    float v = (t >= 0 && t < Tin) ? x[((size_t)b * Tin + t) * 128 + i] : 0.f;
    xt[i][tl] = v;
  }
  __syncthreads();
  int oo = tid & 127, tg = tid >> 7;
  int tb = tg * 32;
  float y[32];
  float bo = bias[oo];
#pragma unroll
  for (int t = 0; t < 32; t++) y[t] = bo;
  for (int i = 0; i < 128; i++) {
    float w0 = wt[0 * 16384 + i * 128 + oo];
    float w1 = wt[1 * 16384 + i * 128 + oo];
    float w2 = wt[2 * 16384 + i * 128 + oo];
    float xm = xt[i][tb], x0 = xt[i][tb + 1];
#pragma unroll
    for (int t = 0; t < 32; t++) {
      float xp = xt[i][tb + t + 2];
      y[t] = fmaf(xm, w0, y[t]);
      y[t] = fmaf(x0, w1, y[t]);
      y[t] = fmaf(xp, w2, y[t]);
      xm = x0; x0 = xp;
    }
  }
  float pooled[16];
#pragma unroll
  for (int j2 = 0; j2 < 16; j2++) {
    float ya = y[2 * j2], yb2 = y[2 * j2 + 1];
    float za = xt[oo][tb + 2 * j2 + 1] + (ya >= 0.f ? ya : 0.01f * ya);
    float zb = xt[oo][tb + 2 * j2 + 2] + (yb2 >= 0.f ? yb2 : 0.01f * yb2);
    pooled[j2] = fmaxf(za, zb);
  }
  __syncthreads();
#pragma unroll
  for (int j2 = 0; j2 < 16; j2++) xt[oo][tg * 16 + j2] = pooled[j2];
  __syncthreads();
  int Tout = Tin >> 1;
  for (int j = tid; j < 128 * 32; j += 256) {
    int tp = j >> 7, cc = j & 127;
    outp[((size_t)b * Tout + (t0 >> 1) + tp) * 128 + cc] = xt[cc][tp];
  }
}

// ---------------------------------------------------------------- final: sum over T=32, dot energy_w
__global__ __launch_bounds__(128) void k_final(const float* __restrict__ x,
                                               const float* __restrict__ ew,
                                               const float* __restrict__ ebb,
                                               float* __restrict__ outp) {
  int b = blockIdx.x, cc = threadIdx.x;
  float s = 0.f;
#pragma unroll
  for (int t = 0; t < 32; t++) s += x[((size_t)b * 32 + t) * 128 + cc];
  float v = s * ew[cc];
#pragma unroll
  for (int m = 1; m < 64; m <<= 1) v += __shfl_xor(v, m);
  __shared__ float red[2];
  if ((cc & 63) == 0) red[cc >> 6] = v;
  __syncthreads();
  if (cc == 0) outp[b] = red[0] + red[1] + ebb[0];
}

// ---------------------------------------------------------------- launch
extern "C" void kernel_launch(void* const* d_in, const int* in_sizes, int n_in,
                              void* d_out, int out_size, void* d_ws, size_t ws_size,
                              hipStream_t stream) {
  (void)in_sizes; (void)n_in; (void)out_size; (void)ws_size;
  const float* tert    = (const float*)d_in[0];
  const float* noise   = (const float*)d_in[3];
  const float* embed_w = (const float*)d_in[4];
  const float* embed_b = (const float*)d_in[5];
  const float* wq = (const float*)d_in[6];
  const float* wk = (const float*)d_in[7];
  const float* wv = (const float*)d_in[8];
  const float* wo = (const float*)d_in[9];
  const float* w1 = (const float*)d_in[10];
  const float* b1 = (const float*)d_in[11];
  const float* w2 = (const float*)d_in[12];
  const float* b2 = (const float*)d_in[13];
  const float* w3 = (const float*)d_in[14];
  const float* b3 = (const float*)d_in[15];
  const float* pw = (const float*)d_in[16];
  const float* pb = (const float*)d_in[17];
  const float* ew = (const float*)d_in[18];
  const float* eb = (const float*)d_in[19];
  float* outp = (float*)d_out;

  float* ws = (float*)d_ws;
  size_t off = 0;
  float* pos  = ws + off; off += 98304;        // N*3
  float* R    = ws + off; off += 294912;       // N*9
  int*   nbr  = (int*)(ws + off); off += 491520;  // N*15
  float* edge = ws + off; off += 14254080;     // N*15*29
  float* h    = ws + off; off += 4194304;      // N*128
  float* q    = ws + off; off += 4194304;
  float* hk   = ws + off; off += 4194304;
  float* hv   = ws + off; off += 4194304;
  float* o    = ws + off; off += 4194304;
  float* wt   = ws + off; off += 196608;       // 4*3*128*128
  float* xa   = ws + off; off += 2097152;      // B*256*128
  float* xb   = ws + off; off += 1048576;      // B*128*128

  k_frames<<<128, 256, 0, stream>>>(tert, pos, R);
  k_knn<<<8192, 256, 0, stream>>>(pos, noise, nbr);
  k_edge<<<1920, 256, 0, stream>>>(pos, R, nbr, edge);
  k_hinit<<<512, 256, 0, stream>>>(embed_w, embed_b, h);
  k_transw<<<768, 256, 0, stream>>>(pw, wt);

  for (int l = 0; l < 3; l++) {
    const float* wq_l = wq + (size_t)l * 128 * 128;
    const float* wk_l = wk + (size_t)l * 157 * 128;
    const float* wv_l = wv + (size_t)l * 157 * 128;
    const float* wo_l = wo + (size_t)l * 128 * 128;
    k_gemm3<<<512, 256, 0, stream>>>(h, wq_l, wk_l, wv_l, q, hk, hv);
    k_attn<<<1024, 256, 0, stream>>>(q, hk, hv, nbr, edge,
                                     wk_l + 128 * 128, wv_l + 128 * 128, o);
    k_gemm<<<512, 256, 0, stream>>>(o, wo_l, nullptr, h, h, 0);
    k_mlp<<<512, 256, 0, stream>>>(h, w1 + (size_t)l * 16384, b1 + l * 128,
                                   w2 + (size_t)l * 16384, b2 + l * 128,
                                   w3 + (size_t)l * 16384, b3 + l * 128);
  }

  k_convpool<<<dim3(8, 64), 256, 0, stream>>>(h,  wt + 0 * 49152, pb + 0,   xa, 512);
  k_convpool<<<dim3(4, 64), 256, 0, stream>>>(xa, wt + 1 * 49152, pb + 128, xb, 256);
  k_convpool<<<dim3(2, 64), 256, 0, stream>>>(xb, wt + 2 * 49152, pb + 256, xa, 128);
  k_convpool<<<dim3(1, 64), 256, 0, stream>>>(xa, wt + 3 * 49152, pb + 384, xb, 64);
  k_final<<<64, 128, 0, stream>>>(xb, ew, eb, outp);
}

// Round 2
// 1401.419 us; speedup vs baseline: 1.1448x; 1.1448x over previous
//
#include <hip/hip_runtime.h>
#include <math.h>

#define N_TOT 32768
#define NNBR 15
#define EDGEF 29

typedef __attribute__((ext_vector_type(8))) short bf16x8;
typedef __attribute__((ext_vector_type(4))) float f32x4;

__device__ __forceinline__ unsigned short f2bf(float x) {
  union { float f; unsigned u; } v; v.f = x;
  unsigned r = v.u + 0x7fff + ((v.u >> 16) & 1);
  return (unsigned short)(r >> 16);
}

// ---------------------------------------------------------------- frames
__global__ __launch_bounds__(256) void k_frames(const float* __restrict__ tert,
                                                float* __restrict__ pos,
                                                float* __restrict__ R) {
  int n = blockIdx.x * 256 + threadIdx.x;
  if (n >= N_TOT) return;
  float px = tert[n * 9 + 3], py = tert[n * 9 + 4], pz = tert[n * 9 + 5];
  pos[n * 3 + 0] = px; pos[n * 3 + 1] = py; pos[n * 3 + 2] = pz;

  int i0 = (n > 0) ? (n - 1) : 0;
  int i1 = (n < N_TOT - 1) ? n : (N_TOT - 2);

  float ax = tert[(i0 + 1) * 9 + 3] - tert[i0 * 9 + 3];
  float ay = tert[(i0 + 1) * 9 + 4] - tert[i0 * 9 + 4];
  float az = tert[(i0 + 1) * 9 + 5] - tert[i0 * 9 + 5];
  float il = 1.f / (sqrtf(ax * ax + ay * ay + az * az) + 1e-8f);
  float ux = ax * il, uy = ay * il, uz = az * il;

  float cx = tert[(i1 + 1) * 9 + 3] - tert[i1 * 9 + 3];
  float cy = tert[(i1 + 1) * 9 + 4] - tert[i1 * 9 + 4];
  float cz = tert[(i1 + 1) * 9 + 5] - tert[i1 * 9 + 5];
  il = 1.f / (sqrtf(cx * cx + cy * cy + cz * cz) + 1e-8f);
  float vx = cx * il, vy = cy * il, vz = cz * il;

  float bx = ux - vx, by = uy - vy, bz = uz - vz;
  il = 1.f / (sqrtf(bx * bx + by * by + bz * bz) + 1e-8f);
  bx *= il; by *= il; bz *= il;

  float nx = uy * vz - uz * vy;
  float ny = uz * vx - ux * vz;
  float nz = ux * vy - uy * vx;
  il = 1.f / (sqrtf(nx * nx + ny * ny + nz * nz) + 1e-8f);
  nx *= il; ny *= il; nz *= il;

  float ex = by * nz - bz * ny;
  float ey = bz * nx - bx * nz;
  float ez = bx * ny - by * nx;

  float* Rn = R + (size_t)n * 9;
  Rn[0] = bx; Rn[1] = nx; Rn[2] = ex;
  Rn[3] = by; Rn[4] = ny; Rn[5] = ey;
  Rn[6] = bz; Rn[7] = nz; Rn[8] = ez;
}

// ---------------------------------------------------------------- kNN
__global__ __launch_bounds__(256) void k_knn(const float* __restrict__ pos,
                                             const float* __restrict__ noise,
                                             int* __restrict__ nbr) {
  int wave = threadIdx.x >> 6, lane = threadIdx.x & 63;
  int row = blockIdx.x * 4 + wave;
  int b = row >> 9;
  float pix = pos[row * 3 + 0], piy = pos[row * 3 + 1], piz = pos[row * 3 + 2];
  float c[8];
  const float* nrow = noise + (size_t)row * 512;
#pragma unroll
  for (int jj = 0; jj < 8; jj++) {
    int j = lane + jj * 64;
    int g = b * 512 + j;
    float dx = pos[g * 3 + 0] - pix;
    float dy = pos[g * 3 + 1] - piy;
    float dz = pos[g * 3 + 2] - piz;
    float dist = sqrtf(dx * dx + dy * dy + dz * dz);
    c[jj] = -dist + 3.f * nrow[j];
  }
  int* outp = nbr + (size_t)row * NNBR;
  for (int it = 0; it < NNBR; it++) {
    float bv = -INFINITY; int bj = 1 << 30;
#pragma unroll
    for (int jj = 0; jj < 8; jj++) {
      int j = lane + jj * 64;
      if (c[jj] > bv || (c[jj] == bv && j < bj)) { bv = c[jj]; bj = j; }
    }
#pragma unroll
    for (int m = 1; m < 64; m <<= 1) {
      float ov = __shfl_xor(bv, m);
      int oj = __shfl_xor(bj, m);
      if (ov > bv || (ov == bv && oj < bj)) { bv = ov; bj = oj; }
    }
    if (lane == (bj & 63)) c[bj >> 6] = -INFINITY;
    if (lane == 0) outp[it] = b * 512 + bj;
  }
}

// ---------------------------------------------------------------- edge features
__global__ __launch_bounds__(256) void k_edge(const float* __restrict__ pos,
                                              const float* __restrict__ R,
                                              const int* __restrict__ nbr,
                                              float* __restrict__ edge) {
  int idx = blockIdx.x * 256 + threadIdx.x;
  if (idx >= N_TOT * NNBR) return;
  int n = idx / NNBR;
  int m = nbr[idx];
  float dx = pos[m * 3 + 0] - pos[n * 3 + 0];
  float dy = pos[m * 3 + 1] - pos[n * 3 + 1];
  float dz = pos[m * 3 + 2] - pos[n * 3 + 2];
  float d = sqrtf(dx * dx + dy * dy + dz * dz);
  float* e = edge + (size_t)idx * EDGEF;
#pragma unroll
  for (int j = 0; j < 16; j++) {
    float mu = (20.f / 15.f) * (float)j;
    float t = (d - mu) * 0.8f;
    e[j] = __expf(-t * t);
  }
  float inv = 1.f / (d + 1e-8f);
  float ux = dx * inv, uy = dy * inv, uz = dz * inv;
  float Rn[9], Rm[9];
#pragma unroll
  for (int j = 0; j < 9; j++) { Rn[j] = R[(size_t)n * 9 + j]; Rm[j] = R[(size_t)m * 9 + j]; }
#pragma unroll
  for (int cc = 0; cc < 3; cc++)
    e[16 + cc] = Rn[0 * 3 + cc] * ux + Rn[1 * 3 + cc] * uy + Rn[2 * 3 + cc] * uz;
#pragma unroll
  for (int cc = 0; cc < 3; cc++)
#pragma unroll
    for (int dd = 0; dd < 3; dd++)
      e[19 + cc * 3 + dd] = Rn[0 * 3 + cc] * Rm[0 * 3 + dd] +
                            Rn[1 * 3 + cc] * Rm[1 * 3 + dd] +
                            Rn[2 * 3 + cc] * Rm[2 * 3 + dd];
  e[28] = (float)(m - n);
}

// ---------------------------------------------------------------- h init
__global__ __launch_bounds__(256) void k_hinit(const float* __restrict__ ew,
                                               const float* __restrict__ ebias,
                                               float* __restrict__ h) {
  __shared__ float hv[128];
  int tid = threadIdx.x;
  if (tid < 128) {
    float s = ebias[tid];
#pragma unroll
    for (int i = 0; i < 27; i++) s += ew[i * 128 + tid];
    hv[tid] = s;
  }
  __syncthreads();
  size_t total = (size_t)N_TOT * 128;
  for (size_t j = (size_t)blockIdx.x * 256 + tid; j < total; j += (size_t)gridDim.x * 256)
    h[j] = hv[j & 127];
}

// ---------------------------------------------------------------- weight prep: fp32 [k][n] -> bf16 [n][k]
__global__ __launch_bounds__(256) void k_prepw(const float* __restrict__ wq, const float* __restrict__ wk,
                                               const float* __restrict__ wv, const float* __restrict__ wo,
                                               const float* __restrict__ w1, const float* __restrict__ w2,
                                               const float* __restrict__ w3, unsigned short* __restrict__ wbt) {
  int idx = blockIdx.x * 256 + threadIdx.x;
  if (idx >= 3 * 7 * 16384) return;
  int l = idx / (7 * 16384);
  int r = idx % (7 * 16384);
  int w = r / 16384;
  int e = r % 16384;
  int k = e >> 7, n = e & 127;
  float val;
  switch (w) {
    case 0: val = wq[(size_t)l * 16384 + e]; break;
    case 1: val = wk[(size_t)l * 157 * 128 + e]; break;  // top 128 rows
    case 2: val = wv[(size_t)l * 157 * 128 + e]; break;
    case 3: val = wo[(size_t)l * 16384 + e]; break;
    case 4: val = w1[(size_t)l * 16384 + e]; break;
    case 5: val = w2[(size_t)l * 16384 + e]; break;
    default: val = w3[(size_t)l * 16384 + e]; break;
  }
  wbt[(size_t)(l * 7 + w) * 16384 + n * 128 + k] = f2bf(val);
}

// ---------------------------------------------------------------- MFMA GEMM: C = relu?(A@W + bias) + res
__global__ __launch_bounds__(256) void k_gemm_m(const float* __restrict__ A,
                                                const unsigned short* __restrict__ Wt,
                                                const float* __restrict__ bias,
                                                const float* __restrict__ res,
                                                float* __restrict__ C, int relu) {
  __shared__ unsigned short As[64 * 136];
  __shared__ unsigned short Ws[128 * 136];
  int tid = threadIdx.x;
  int r0 = blockIdx.x * 64;
  for (int j = tid; j < 2048; j += 256) {
    int row = j >> 5, c4 = (j & 31) * 4;
    float4 v = *(const float4*)(A + (size_t)(r0 + row) * 128 + c4);
    unsigned short* d = &As[row * 136 + c4];
    d[0] = f2bf(v.x); d[1] = f2bf(v.y); d[2] = f2bf(v.z); d[3] = f2bf(v.w);
  }
  for (int j = tid; j < 4096; j += 256) {
    int row = j >> 5, c4 = (j & 31) * 4;
    *(ushort4*)&Ws[row * 136 + c4] = *(const ushort4*)(Wt + row * 128 + c4);
  }
  __syncthreads();
  int lane = tid & 63;
  int quad = lane >> 4, l16 = lane & 15;
  int wrow = (tid >> 6) * 16;
  f32x4 acc[8];
#pragma unroll
  for (int t = 0; t < 8; t++) acc[t] = (f32x4){0.f, 0.f, 0.f, 0.f};
#pragma unroll
  for (int kk = 0; kk < 4; kk++) {
    bf16x8 a = *(const bf16x8*)&As[(wrow + l16) * 136 + kk * 32 + quad * 8];
#pragma unroll
    for (int t = 0; t < 8; t++) {
      bf16x8 b = *(const bf16x8*)&Ws[(t * 16 + l16) * 136 + kk * 32 + quad * 8];
      acc[t] = __builtin_amdgcn_mfma_f32_16x16x32_bf16(a, b, acc[t], 0, 0, 0);
    }
  }
#pragma unroll
  for (int t = 0; t < 8; t++) {
    int col = t * 16 + l16;
    float bv = bias ? bias[col] : 0.f;
#pragma unroll
    for (int r = 0; r < 4; r++) {
      size_t oo = (size_t)(r0 + wrow + quad * 4 + r) * 128 + col;
      float v = acc[t][r] + bv;
      if (relu) v = fmaxf(v, 0.f);
      if (res) v += res[oo];
      C[oo] = v;
    }
  }
}

// ---------------------------------------------------------------- MFMA triple GEMM (q, hk, hv)
__global__ __launch_bounds__(256) void k_gemm3m(const float* __restrict__ A,
                                                const unsigned short* __restrict__ Wt0,
                                                const unsigned short* __restrict__ Wt1,
                                                const unsigned short* __restrict__ Wt2,
                                                float* __restrict__ C0, float* __restrict__ C1,
                                                float* __restrict__ C2) {
  __shared__ unsigned short As[64 * 136];
  __shared__ unsigned short Ws[128 * 136];
  int tid = threadIdx.x;
  int r0 = blockIdx.x * 64;
  for (int j = tid; j < 2048; j += 256) {
    int row = j >> 5, c4 = (j & 31) * 4;
    float4 v = *(const float4*)(A + (size_t)(r0 + row) * 128 + c4);
    unsigned short* d = &As[row * 136 + c4];
    d[0] = f2bf(v.x); d[1] = f2bf(v.y); d[2] = f2bf(v.z); d[3] = f2bf(v.w);
  }
  int lane = tid & 63;
  int quad = lane >> 4, l16 = lane & 15;
  int wrow = (tid >> 6) * 16;
  const unsigned short* wts[3] = {Wt0, Wt1, Wt2};
  float* cs[3] = {C0, C1, C2};
  for (int w = 0; w < 3; w++) {
    __syncthreads();
    const unsigned short* Wt = wts[w];
    for (int j = tid; j < 4096; j += 256) {
      int row = j >> 5, c4 = (j & 31) * 4;
      *(ushort4*)&Ws[row * 136 + c4] = *(const ushort4*)(Wt + row * 128 + c4);
    }
    __syncthreads();
    f32x4 acc[8];
#pragma unroll
    for (int t = 0; t < 8; t++) acc[t] = (f32x4){0.f, 0.f, 0.f, 0.f};
#pragma unroll
    for (int kk = 0; kk < 4; kk++) {
      bf16x8 a = *(const bf16x8*)&As[(wrow + l16) * 136 + kk * 32 + quad * 8];
#pragma unroll
      for (int t = 0; t < 8; t++) {
        bf16x8 b = *(const bf16x8*)&Ws[(t * 16 + l16) * 136 + kk * 32 + quad * 8];
        acc[t] = __builtin_amdgcn_mfma_f32_16x16x32_bf16(a, b, acc[t], 0, 0, 0);
      }
    }
    float* C = cs[w];
#pragma unroll
    for (int t = 0; t < 8; t++) {
      int col = t * 16 + l16;
#pragma unroll
      for (int r = 0; r < 4; r++)
        C[(size_t)(r0 + wrow + quad * 4 + r) * 128 + col] = acc[t][r];
    }
  }
}

// ---------------------------------------------------------------- MFMA fused MLP: h += W3(relu(W2(relu(W1h+b1))+b2))+b3
__global__ __launch_bounds__(256) void k_mlp_m(float* __restrict__ h,
                                               const unsigned short* __restrict__ W1t, const float* __restrict__ B1,
                                               const unsigned short* __restrict__ W2t, const float* __restrict__ B2,
                                               const unsigned short* __restrict__ W3t, const float* __restrict__ B3) {
  __shared__ unsigned short As[64 * 136];
  __shared__ unsigned short Bs[64 * 136];
  __shared__ unsigned short Ws[128 * 136];
  int tid = threadIdx.x;
  int r0 = blockIdx.x * 64;
  for (int j = tid; j < 2048; j += 256) {
    int row = j >> 5, c4 = (j & 31) * 4;
    float4 v = *(const float4*)(h + (size_t)(r0 + row) * 128 + c4);
    unsigned short* d = &As[row * 136 + c4];
    d[0] = f2bf(v.x); d[1] = f2bf(v.y); d[2] = f2bf(v.z); d[3] = f2bf(v.w);
  }
  for (int j = tid; j < 4096; j += 256) {
    int row = j >> 5, c4 = (j & 31) * 4;
    *(ushort4*)&Ws[row * 136 + c4] = *(const ushort4*)(W1t + row * 128 + c4);
  }
  __syncthreads();
  int lane = tid & 63;
  int quad = lane >> 4, l16 = lane & 15;
  int wrow = (tid >> 6) * 16;
  f32x4 acc[8];

  // stage 1: Bs = bf16(relu(As@W1 + b1))
#pragma unroll
  for (int t = 0; t < 8; t++) acc[t] = (f32x4){0.f, 0.f, 0.f, 0.f};
#pragma unroll
  for (int kk = 0; kk < 4; kk++) {
    bf16x8 a = *(const bf16x8*)&As[(wrow + l16) * 136 + kk * 32 + quad * 8];
#pragma unroll
    for (int t = 0; t < 8; t++) {
      bf16x8 b = *(const bf16x8*)&Ws[(t * 16 + l16) * 136 + kk * 32 + quad * 8];
      acc[t] = __builtin_amdgcn_mfma_f32_16x16x32_bf16(a, b, acc[t], 0, 0, 0);
    }
  }
#pragma unroll
  for (int t = 0; t < 8; t++) {
    int col = t * 16 + l16;
    float bv = B1[col];
#pragma unroll
    for (int r = 0; r < 4; r++)
      Bs[(wrow + quad * 4 + r) * 136 + col] = f2bf(fmaxf(acc[t][r] + bv, 0.f));
  }
  __syncthreads();
  for (int j = tid; j < 4096; j += 256) {
    int row = j >> 5, c4 = (j & 31) * 4;
    *(ushort4*)&Ws[row * 136 + c4] = *(const ushort4*)(W2t + row * 128 + c4);
  }
  __syncthreads();

  // stage 2: As = bf16(relu(Bs@W2 + b2))
#pragma unroll
  for (int t = 0; t < 8; t++) acc[t] = (f32x4){0.f, 0.f, 0.f, 0.f};
#pragma unroll
  for (int kk = 0; kk < 4; kk++) {
    bf16x8 a = *(const bf16x8*)&Bs[(wrow + l16) * 136 + kk * 32 + quad * 8];
#pragma unroll
    for (int t = 0; t < 8; t++) {
      bf16x8 b = *(const bf16x8*)&Ws[(t * 16 + l16) * 136 + kk * 32 + quad * 8];
      acc[t] = __builtin_amdgcn_mfma_f32_16x16x32_bf16(a, b, acc[t], 0, 0, 0);
    }
  }
#pragma unroll
  for (int t = 0; t < 8; t++) {
    int col = t * 16 + l16;
    float bv = B2[col];
#pragma unroll
    for (int r = 0; r < 4; r++)
      As[(wrow + quad * 4 + r) * 136 + col] = f2bf(fmaxf(acc[t][r] + bv, 0.f));
  }
  __syncthreads();
  for (int j = tid; j < 4096; j += 256) {
    int row = j >> 5, c4 = (j & 31) * 4;
    *(ushort4*)&Ws[row * 136 + c4] = *(const ushort4*)(W3t + row * 128 + c4);
  }
  __syncthreads();

  // stage 3: h += As@W3 + b3
#pragma unroll
  for (int t = 0; t < 8; t++) acc[t] = (f32x4){0.f, 0.f, 0.f, 0.f};
#pragma unroll
  for (int kk = 0; kk < 4; kk++) {
    bf16x8 a = *(const bf16x8*)&As[(wrow + l16) * 136 + kk * 32 + quad * 8];
#pragma unroll
    for (int t = 0; t < 8; t++) {
      bf16x8 b = *(const bf16x8*)&Ws[(t * 16 + l16) * 136 + kk * 32 + quad * 8];
      acc[t] = __builtin_amdgcn_mfma_f32_16x16x32_bf16(a, b, acc[t], 0, 0, 0);
    }
  }
#pragma unroll
  for (int t = 0; t < 8; t++) {
    int col = t * 16 + l16;
    float bv = B3[col];
#pragma unroll
    for (int r = 0; r < 4; r++) {
      size_t oo = (size_t)(r0 + wrow + quad * 4 + r) * 128 + col;
      h[oo] += acc[t][r] + bv;
    }
  }
}

// ---------------------------------------------------------------- attention: 2-pass, all-neighbor ILP
#define NPW 4
__global__ __launch_bounds__(256) void k_attn(const float* __restrict__ q,
                                              const float* __restrict__ hk,
                                              const float* __restrict__ hv,
                                              const int* __restrict__ nbr,
                                              const float* __restrict__ edge,
                                              const float* __restrict__ wkb,
                                              const float* __restrict__ wvb,
                                              float* __restrict__ o) {
  __shared__ float elds[4][NNBR * 32];
  int wave = threadIdx.x >> 6, lane = threadIdx.x & 63;
  int c2 = lane * 2;
  float2 wkr[EDGEF], wvr[EDGEF];
#pragma unroll
  for (int e = 0; e < EDGEF; e++) {
    wkr[e] = *(const float2*)(wkb + e * 128 + c2);
    wvr[e] = *(const float2*)(wvb + e * 128 + c2);
  }
  float* el = elds[wave];
  int n0 = (blockIdx.x * 4 + wave) * NPW;
#pragma unroll 1
  for (int ni = 0; ni < NPW; ni++) {
    int n = n0 + ni;
    const float* esrc = edge + (size_t)n * (NNBR * EDGEF);
#pragma unroll
    for (int jj = 0; jj < 7; jj++) {
      int j = lane + jj * 64;
      if (j < NNBR * EDGEF) el[(j / EDGEF) * 32 + (j % EDGEF)] = esrc[j];
    }
    __asm__ volatile("s_waitcnt lgkmcnt(0)" ::: "memory");
    const int* nb = nbr + (size_t)n * NNBR;
    int m[NNBR];
#pragma unroll
    for (int k = 0; k < NNBR; k++) m[k] = nb[k];
    float2 q2 = *(const float2*)(q + (size_t)n * 128 + c2);
    q2.x *= 0.25f; q2.y *= 0.25f;
    float lg[NNBR];
#pragma unroll
    for (int k = 0; k < NNBR; k++) {
      float2 kk = *(const float2*)(hk + (size_t)m[k] * 128 + c2);
      const float* ep = el + k * 32;
      float ev[32];
#pragma unroll
      for (int j4 = 0; j4 < 8; j4++) *(float4*)&ev[j4 * 4] = *(const float4*)(ep + j4 * 4);
      float kx = kk.x, ky = kk.y;
#pragma unroll
      for (int e = 0; e < EDGEF; e++) {
        kx = fmaf(ev[e], wkr[e].x, kx);
        ky = fmaf(ev[e], wkr[e].y, ky);
      }
      float d = q2.x * kx + q2.y * ky;
      d += __shfl_xor(d, 1);
      d += __shfl_xor(d, 2);
      d += __shfl_xor(d, 4);
      lg[k] = d;
    }
    float mx = lg[0];
#pragma unroll
    for (int k = 1; k < NNBR; k++) mx = fmaxf(mx, lg[k]);
    float p[NNBR], s = 0.f;
#pragma unroll
    for (int k = 0; k < NNBR; k++) { p[k] = __expf(lg[k] - mx); s += p[k]; }
    float inv = 1.f / s;
    float ox = 0.f, oy = 0.f;
#pragma unroll
    for (int k = 0; k < NNBR; k++) {
      float2 vv = *(const float2*)(hv + (size_t)m[k] * 128 + c2);
      const float* ep = el + k * 32;
      float ev[32];
#pragma unroll
      for (int j4 = 0; j4 < 8; j4++) *(float4*)&ev[j4 * 4] = *(const float4*)(ep + j4 * 4);
      float vx = vv.x, vy = vv.y;
#pragma unroll
      for (int e = 0; e < EDGEF; e++) {
        vx = fmaf(ev[e], wvr[e].x, vx);
        vy = fmaf(ev[e], wvr[e].y, vy);
      }
      ox = fmaf(p[k], vx, ox);
      oy = fmaf(p[k], vy, oy);
    }
    *(float2*)(o + (size_t)n * 128 + c2) = make_float2(ox * inv, oy * inv);
  }
}

// ---------------------------------------------------------------- pool-weight transpose (s,o,i,kt) -> (s,kt,i,o)
__global__ __launch_bounds__(256) void k_transw(const float* __restrict__ pw, float* __restrict__ wt) {
  int idx = blockIdx.x * 256 + threadIdx.x;
  if (idx >= 4 * 128 * 128 * 3) return;
  int kt = idx % 3;
  int rest = idx / 3;
  int i = rest % 128; rest /= 128;
  int oo = rest % 128;
  int s = rest / 128;
  wt[(((size_t)s * 3 + kt) * 128 + i) * 128 + oo] = pw[idx];
}

// ---------------------------------------------------------------- conv+leaky+residual+maxpool2
__global__ __launch_bounds__(256) void k_convpool(const float* __restrict__ x,
                                                  const float* __restrict__ wt,
                                                  const float* __restrict__ bias,
                                                  float* __restrict__ outp, int Tin) {
  __shared__ float xt[128][67];
  int b = blockIdx.y;
  int t0 = blockIdx.x * 64;
  int tid = threadIdx.x;
  for (int j = tid; j < 128 * 66; j += 256) {
    int tl = j >> 7, i = j & 127;
    int t = t0 - 1 + tl;
    float v = (t >= 0 && t < Tin) ? x[((size_t)b * Tin + t) * 128 + i] : 0.f;
    xt[i][tl] = v;
  }
  __syncthreads();
  int oo = tid & 127, tg = tid >> 7;
  int tb = tg * 32;
  float y[32];
  float bo = bias[oo];
#pragma unroll
  for (int t = 0; t < 32; t++) y[t] = bo;
  for (int i = 0; i < 128; i++) {
    float w0 = wt[0 * 16384 + i * 128 + oo];
    float w1 = wt[1 * 16384 + i * 128 + oo];
    float w2 = wt[2 * 16384 + i * 128 + oo];
    float xm = xt[i][tb], x0 = xt[i][tb + 1];
#pragma unroll
    for (int t = 0; t < 32; t++) {
      float xp = xt[i][tb + t + 2];
      y[t] = fmaf(xm, w0, y[t]);
      y[t] = fmaf(x0, w1, y[t]);
      y[t] = fmaf(xp, w2, y[t]);
      xm = x0; x0 = xp;
    }
  }
  float pooled[16];
#pragma unroll
  for (int j2 = 0; j2 < 16; j2++) {
    float ya = y[2 * j2], yb2 = y[2 * j2 + 1];
    float za = xt[oo][tb + 2 * j2 + 1] + (ya >= 0.f ? ya : 0.01f * ya);
    float zb = xt[oo][tb + 2 * j2 + 2] + (yb2 >= 0.f ? yb2 : 0.01f * yb2);
    pooled[j2] = fmaxf(za, zb);
  }
  __syncthreads();
#pragma unroll
  for (int j2 = 0; j2 < 16; j2++) xt[oo][tg * 16 + j2] = pooled[j2];
  __syncthreads();
  int Tout = Tin >> 1;
  for (int j = tid; j < 128 * 32; j += 256) {
    int tp = j >> 7, cc = j & 127;
    outp[((size_t)b * Tout + (t0 >> 1) + tp) * 128 + cc] = xt[cc][tp];
  }
}

// ---------------------------------------------------------------- final reduce
__global__ __launch_bounds__(128) void k_final(const float* __restrict__ x,
                                               const float* __restrict__ ew,
                                               const float* __restrict__ ebb,
                                               float* __restrict__ outp) {
  int b = blockIdx.x, cc = threadIdx.x;
  float s = 0.f;
#pragma unroll
  for (int t = 0; t < 32; t++) s += x[((size_t)b * 32 + t) * 128 + cc];
  float v = s * ew[cc];
#pragma unroll
  for (int m = 1; m < 64; m <<= 1) v += __shfl_xor(v, m);
  __shared__ float red[2];
  if ((cc & 63) == 0) red[cc >> 6] = v;
  __syncthreads();
  if (cc == 0) outp[b] = red[0] + red[1] + ebb[0];
}

// ---------------------------------------------------------------- launch
extern "C" void kernel_launch(void* const* d_in, const int* in_sizes, int n_in,
                              void* d_out, int out_size, void* d_ws, size_t ws_size,
                              hipStream_t stream) {
  (void)in_sizes; (void)n_in; (void)out_size; (void)ws_size;
  const float* tert    = (const float*)d_in[0];
  const float* noise   = (const float*)d_in[3];
  const float* embed_w = (const float*)d_in[4];
  const float* embed_b = (const float*)d_in[5];
  const float* wq = (const float*)d_in[6];
  const float* wk = (const float*)d_in[7];
  const float* wv = (const float*)d_in[8];
  const float* wo = (const float*)d_in[9];
  const float* w1 = (const float*)d_in[10];
  const float* b1 = (const float*)d_in[11];
  const float* w2 = (const float*)d_in[12];
  const float* b2 = (const float*)d_in[13];
  const float* w3 = (const float*)d_in[14];
  const float* b3 = (const float*)d_in[15];
  const float* pw = (const float*)d_in[16];
  const float* pb = (const float*)d_in[17];
  const float* ew = (const float*)d_in[18];
  const float* eb = (const float*)d_in[19];
  float* outp = (float*)d_out;

  float* ws = (float*)d_ws;
  size_t off = 0;
  float* pos  = ws + off; off += 98304;
  float* R    = ws + off; off += 294912;
  int*   nbr  = (int*)(ws + off); off += 491520;
  float* edge = ws + off; off += 14254080;
  float* h    = ws + off; off += 4194304;
  float* q    = ws + off; off += 4194304;
  float* hk   = ws + off; off += 4194304;
  float* hv   = ws + off; off += 4194304;
  float* o    = ws + off; off += 4194304;
  float* wt   = ws + off; off += 196608;
  float* xa   = ws + off; off += 2097152;
  float* xb   = ws + off; off += 1048576;
  unsigned short* wbt = (unsigned short*)(ws + off); off += 172032;  // 3*7*16384 bf16

  k_frames<<<128, 256, 0, stream>>>(tert, pos, R);
  k_knn<<<8192, 256, 0, stream>>>(pos, noise, nbr);
  k_edge<<<1920, 256, 0, stream>>>(pos, R, nbr, edge);
  k_hinit<<<512, 256, 0, stream>>>(embed_w, embed_b, h);
  k_transw<<<768, 256, 0, stream>>>(pw, wt);
  k_prepw<<<1344, 256, 0, stream>>>(wq, wk, wv, wo, w1, w2, w3, wbt);

  for (int l = 0; l < 3; l++) {
    const unsigned short* wtq = wbt + (size_t)(l * 7 + 0) * 16384;
    const unsigned short* wtk = wbt + (size_t)(l * 7 + 1) * 16384;
    const unsigned short* wtv = wbt + (size_t)(l * 7 + 2) * 16384;
    const unsigned short* wto = wbt + (size_t)(l * 7 + 3) * 16384;
    const unsigned short* wt1 = wbt + (size_t)(l * 7 + 4) * 16384;
    const unsigned short* wt2 = wbt + (size_t)(l * 7 + 5) * 16384;
    const unsigned short* wt3 = wbt + (size_t)(l * 7 + 6) * 16384;
    const float* wk_l = wk + (size_t)l * 157 * 128;
    const float* wv_l = wv + (size_t)l * 157 * 128;

    k_gemm3m<<<512, 256, 0, stream>>>(h, wtq, wtk, wtv, q, hk, hv);
    k_attn<<<2048, 256, 0, stream>>>(q, hk, hv, nbr, edge,
                                     wk_l + 128 * 128, wv_l + 128 * 128, o);
    k_gemm_m<<<512, 256, 0, stream>>>(o, wto, nullptr, h, h, 0);
    k_mlp_m<<<512, 256, 0, stream>>>(h, wt1, b1 + l * 128, wt2, b2 + l * 128,
                                     wt3, b3 + l * 128);
  }

  k_convpool<<<dim3(8, 64), 256, 0, stream>>>(h,  wt + 0 * 49152, pb + 0,   xa, 512);
  k_convpool<<<dim3(4, 64), 256, 0, stream>>>(xa, wt + 1 * 49152, pb + 128, xb, 256);
  k_convpool<<<dim3(2, 64), 256, 0, stream>>>(xb, wt + 2 * 49152, pb + 256, xa, 128);
  k_convpool<<<dim3(1, 64), 256, 0, stream>>>(xa, wt + 3 * 49152, pb + 384, xb, 64);
  k_final<<<64, 128, 0, stream>>>(xb, ew, eb, outp);
}

// Round 3
// 850.510 us; speedup vs baseline: 1.8864x; 1.6477x over previous
//
#include <hip/hip_runtime.h>
#include <math.h>

#define N_TOT 32768
#define NNBR 15
#define EDGEF 29

typedef __attribute__((ext_vector_type(8))) _Float16 f16x8;
typedef __attribute__((ext_vector_type(4))) float f32x4;

#define WSYNC() __asm__ volatile("s_waitcnt lgkmcnt(0)" ::: "memory")

__device__ __forceinline__ _Float16 f2h(float x) { return (_Float16)x; }

// ---------------------------------------------------------------- frames
__global__ __launch_bounds__(256) void k_frames(const float* __restrict__ tert,
                                                float* __restrict__ pos,
                                                float* __restrict__ R) {
  int n = blockIdx.x * 256 + threadIdx.x;
  if (n >= N_TOT) return;
  float px = tert[n * 9 + 3], py = tert[n * 9 + 4], pz = tert[n * 9 + 5];
  pos[n * 3 + 0] = px; pos[n * 3 + 1] = py; pos[n * 3 + 2] = pz;

  int i0 = (n > 0) ? (n - 1) : 0;
  int i1 = (n < N_TOT - 1) ? n : (N_TOT - 2);

  float ax = tert[(i0 + 1) * 9 + 3] - tert[i0 * 9 + 3];
  float ay = tert[(i0 + 1) * 9 + 4] - tert[i0 * 9 + 4];
  float az = tert[(i0 + 1) * 9 + 5] - tert[i0 * 9 + 5];
  float il = 1.f / (sqrtf(ax * ax + ay * ay + az * az) + 1e-8f);
  float ux = ax * il, uy = ay * il, uz = az * il;

  float cx = tert[(i1 + 1) * 9 + 3] - tert[i1 * 9 + 3];
  float cy = tert[(i1 + 1) * 9 + 4] - tert[i1 * 9 + 4];
  float cz = tert[(i1 + 1) * 9 + 5] - tert[i1 * 9 + 5];
  il = 1.f / (sqrtf(cx * cx + cy * cy + cz * cz) + 1e-8f);
  float vx = cx * il, vy = cy * il, vz = cz * il;

  float bx = ux - vx, by = uy - vy, bz = uz - vz;
  il = 1.f / (sqrtf(bx * bx + by * by + bz * bz) + 1e-8f);
  bx *= il; by *= il; bz *= il;

  float nx = uy * vz - uz * vy;
  float ny = uz * vx - ux * vz;
  float nz = ux * vy - uy * vx;
  il = 1.f / (sqrtf(nx * nx + ny * ny + nz * nz) + 1e-8f);
  nx *= il; ny *= il; nz *= il;

  float ex = by * nz - bz * ny;
  float ey = bz * nx - bx * nz;
  float ez = bx * ny - by * nx;

  float* Rn = R + (size_t)n * 9;
  Rn[0] = bx; Rn[1] = nx; Rn[2] = ex;
  Rn[3] = by; Rn[4] = ny; Rn[5] = ey;
  Rn[6] = bz; Rn[7] = nz; Rn[8] = ez;
}

// ---------------------------------------------------------------- kNN
__global__ __launch_bounds__(256) void k_knn(const float* __restrict__ pos,
                                             const float* __restrict__ noise,
                                             int* __restrict__ nbr) {
  int wave = threadIdx.x >> 6, lane = threadIdx.x & 63;
  int row = blockIdx.x * 4 + wave;
  int b = row >> 9;
  float pix = pos[row * 3 + 0], piy = pos[row * 3 + 1], piz = pos[row * 3 + 2];
  float c[8];
  const float* nrow = noise + (size_t)row * 512;
#pragma unroll
  for (int jj = 0; jj < 8; jj++) {
    int j = lane + jj * 64;
    int g = b * 512 + j;
    float dx = pos[g * 3 + 0] - pix;
    float dy = pos[g * 3 + 1] - piy;
    float dz = pos[g * 3 + 2] - piz;
    float dist = sqrtf(dx * dx + dy * dy + dz * dz);
    c[jj] = -dist + 3.f * nrow[j];
  }
  int* outp = nbr + (size_t)row * NNBR;
  for (int it = 0; it < NNBR; it++) {
    float bv = -INFINITY; int bj = 1 << 30;
#pragma unroll
    for (int jj = 0; jj < 8; jj++) {
      int j = lane + jj * 64;
      if (c[jj] > bv || (c[jj] == bv && j < bj)) { bv = c[jj]; bj = j; }
    }
#pragma unroll
    for (int m = 1; m < 64; m <<= 1) {
      float ov = __shfl_xor(bv, m);
      int oj = __shfl_xor(bj, m);
      if (ov > bv || (ov == bv && oj < bj)) { bv = ov; bj = oj; }
    }
    if (lane == (bj & 63)) c[bj >> 6] = -INFINITY;
    if (lane == 0) outp[it] = b * 512 + bj;
  }
}

// ---------------------------------------------------------------- edge features
__global__ __launch_bounds__(256) void k_edge(const float* __restrict__ pos,
                                              const float* __restrict__ R,
                                              const int* __restrict__ nbr,
                                              float* __restrict__ edge) {
  int idx = blockIdx.x * 256 + threadIdx.x;
  if (idx >= N_TOT * NNBR) return;
  int n = idx / NNBR;
  int m = nbr[idx];
  float dx = pos[m * 3 + 0] - pos[n * 3 + 0];
  float dy = pos[m * 3 + 1] - pos[n * 3 + 1];
  float dz = pos[m * 3 + 2] - pos[n * 3 + 2];
  float d = sqrtf(dx * dx + dy * dy + dz * dz);
  float* e = edge + (size_t)idx * EDGEF;
#pragma unroll
  for (int j = 0; j < 16; j++) {
    float mu = (20.f / 15.f) * (float)j;
    float t = (d - mu) * 0.8f;
    e[j] = __expf(-t * t);
  }
  float inv = 1.f / (d + 1e-8f);
  float ux = dx * inv, uy = dy * inv, uz = dz * inv;
  float Rn[9], Rm[9];
#pragma unroll
  for (int j = 0; j < 9; j++) { Rn[j] = R[(size_t)n * 9 + j]; Rm[j] = R[(size_t)m * 9 + j]; }
#pragma unroll
  for (int cc = 0; cc < 3; cc++)
    e[16 + cc] = Rn[0 * 3 + cc] * ux + Rn[1 * 3 + cc] * uy + Rn[2 * 3 + cc] * uz;
#pragma unroll
  for (int cc = 0; cc < 3; cc++)
#pragma unroll
    for (int dd = 0; dd < 3; dd++)
      e[19 + cc * 3 + dd] = Rn[0 * 3 + cc] * Rm[0 * 3 + dd] +
                            Rn[1 * 3 + cc] * Rm[1 * 3 + dd] +
                            Rn[2 * 3 + cc] * Rm[2 * 3 + dd];
  e[28] = (float)(m - n);
}

// ---------------------------------------------------------------- h init
__global__ __launch_bounds__(256) void k_hinit(const float* __restrict__ ew,
                                               const float* __restrict__ ebias,
                                               float* __restrict__ h) {
  __shared__ float hv[128];
  int tid = threadIdx.x;
  if (tid < 128) {
    float s = ebias[tid];
#pragma unroll
    for (int i = 0; i < 27; i++) s += ew[i * 128 + tid];
    hv[tid] = s;
  }
  __syncthreads();
  size_t total = (size_t)N_TOT * 128;
  for (size_t j = (size_t)blockIdx.x * 256 + tid; j < total; j += (size_t)gridDim.x * 256)
    h[j] = hv[j & 127];
}

// ---------------------------------------------------------------- dense weight prep: fp32 [k][n] -> fp16 [n][k]
__global__ __launch_bounds__(256) void k_prepw(const float* __restrict__ wq, const float* __restrict__ wk,
                                               const float* __restrict__ wv, const float* __restrict__ wo,
                                               const float* __restrict__ w1, const float* __restrict__ w2,
                                               const float* __restrict__ w3, _Float16* __restrict__ wbt) {
  int idx = blockIdx.x * 256 + threadIdx.x;
  if (idx >= 3 * 7 * 16384) return;
  int l = idx / (7 * 16384);
  int r = idx % (7 * 16384);
  int w = r / 16384;
  int e = r % 16384;
  int k = e >> 7, n = e & 127;
  float val;
  switch (w) {
    case 0: val = wq[(size_t)l * 16384 + e]; break;
    case 1: val = wk[(size_t)l * 157 * 128 + e]; break;
    case 2: val = wv[(size_t)l * 157 * 128 + e]; break;
    case 3: val = wo[(size_t)l * 16384 + e]; break;
    case 4: val = w1[(size_t)l * 16384 + e]; break;
    case 5: val = w2[(size_t)l * 16384 + e]; break;
    default: val = w3[(size_t)l * 16384 + e]; break;
  }
  wbt[(size_t)(l * 7 + w) * 16384 + n * 128 + k] = f2h(val);
}

// ---------------------------------------------------------------- conv weight prep: (s,o,i,kt) fp32 -> fp16 [s][kt][o][i]
__global__ __launch_bounds__(256) void k_prepcw(const float* __restrict__ pw, _Float16* __restrict__ wc) {
  int idx = blockIdx.x * 256 + threadIdx.x;
  if (idx >= 4 * 128 * 128 * 3) return;
  int kt = idx % 3;
  int rest = idx / 3;
  int i = rest % 128; rest /= 128;
  int oo = rest % 128;
  int s = rest / 128;
  wc[(((size_t)s * 3 + kt) * 128 + oo) * 128 + i] = f2h(pw[idx]);
}

// ---------------------------------------------------------------- MFMA GEMM: C = relu?(A@W + bias) + res
__global__ __launch_bounds__(256) void k_gemm_m(const float* __restrict__ A,
                                                const _Float16* __restrict__ Wt,
                                                const float* __restrict__ bias,
                                                const float* __restrict__ res,
                                                float* __restrict__ C, int relu) {
  __shared__ _Float16 As[64 * 136];
  __shared__ _Float16 Ws[128 * 136];
  int tid = threadIdx.x;
  int r0 = blockIdx.x * 64;
  for (int j = tid; j < 2048; j += 256) {
    int row = j >> 5, c4 = (j & 31) * 4;
    float4 v = *(const float4*)(A + (size_t)(r0 + row) * 128 + c4);
    _Float16* d = &As[row * 136 + c4];
    d[0] = f2h(v.x); d[1] = f2h(v.y); d[2] = f2h(v.z); d[3] = f2h(v.w);
  }
  for (int j = tid; j < 4096; j += 256) {
    int row = j >> 5, c4 = (j & 31) * 4;
    *(ushort4*)&Ws[row * 136 + c4] = *(const ushort4*)(Wt + row * 128 + c4);
  }
  __syncthreads();
  int lane = tid & 63;
  int quad = lane >> 4, l16 = lane & 15;
  int wrow = (tid >> 6) * 16;
  f32x4 acc[8];
#pragma unroll
  for (int t = 0; t < 8; t++) acc[t] = (f32x4){0.f, 0.f, 0.f, 0.f};
#pragma unroll
  for (int kk = 0; kk < 4; kk++) {
    f16x8 a = *(const f16x8*)&As[(wrow + l16) * 136 + kk * 32 + quad * 8];
#pragma unroll
    for (int t = 0; t < 8; t++) {
      f16x8 b = *(const f16x8*)&Ws[(t * 16 + l16) * 136 + kk * 32 + quad * 8];
      acc[t] = __builtin_amdgcn_mfma_f32_16x16x32_f16(a, b, acc[t], 0, 0, 0);
    }
  }
#pragma unroll
  for (int t = 0; t < 8; t++) {
    int col = t * 16 + l16;
    float bv = bias ? bias[col] : 0.f;
#pragma unroll
    for (int r = 0; r < 4; r++) {
      size_t oo = (size_t)(r0 + wrow + quad * 4 + r) * 128 + col;
      float v = acc[t][r] + bv;
      if (relu) v = fmaxf(v, 0.f);
      if (res) v += res[oo];
      C[oo] = v;
    }
  }
}

// ---------------------------------------------------------------- MFMA triple GEMM (q, hk, hv)
__global__ __launch_bounds__(256) void k_gemm3m(const float* __restrict__ A,
                                                const _Float16* __restrict__ Wt0,
                                                const _Float16* __restrict__ Wt1,
                                                const _Float16* __restrict__ Wt2,
                                                float* __restrict__ C0, float* __restrict__ C1,
                                                float* __restrict__ C2) {
  __shared__ _Float16 As[64 * 136];
  __shared__ _Float16 Ws[128 * 136];
  int tid = threadIdx.x;
  int r0 = blockIdx.x * 64;
  for (int j = tid; j < 2048; j += 256) {
    int row = j >> 5, c4 = (j & 31) * 4;
    float4 v = *(const float4*)(A + (size_t)(r0 + row) * 128 + c4);
    _Float16* d = &As[row * 136 + c4];
    d[0] = f2h(v.x); d[1] = f2h(v.y); d[2] = f2h(v.z); d[3] = f2h(v.w);
  }
  int lane = tid & 63;
  int quad = lane >> 4, l16 = lane & 15;
  int wrow = (tid >> 6) * 16;
  const _Float16* wts[3] = {Wt0, Wt1, Wt2};
  float* cs[3] = {C0, C1, C2};
  for (int w = 0; w < 3; w++) {
    __syncthreads();
    const _Float16* Wt = wts[w];
    for (int j = tid; j < 4096; j += 256) {
      int row = j >> 5, c4 = (j & 31) * 4;
      *(ushort4*)&Ws[row * 136 + c4] = *(const ushort4*)(Wt + row * 128 + c4);
    }
    __syncthreads();
    f32x4 acc[8];
#pragma unroll
    for (int t = 0; t < 8; t++) acc[t] = (f32x4){0.f, 0.f, 0.f, 0.f};
#pragma unroll
    for (int kk = 0; kk < 4; kk++) {
      f16x8 a = *(const f16x8*)&As[(wrow + l16) * 136 + kk * 32 + quad * 8];
#pragma unroll
      for (int t = 0; t < 8; t++) {
        f16x8 b = *(const f16x8*)&Ws[(t * 16 + l16) * 136 + kk * 32 + quad * 8];
        acc[t] = __builtin_amdgcn_mfma_f32_16x16x32_f16(a, b, acc[t], 0, 0, 0);
      }
    }
    float* C = cs[w];
#pragma unroll
    for (int t = 0; t < 8; t++) {
      int col = t * 16 + l16;
#pragma unroll
      for (int r = 0; r < 4; r++)
        C[(size_t)(r0 + wrow + quad * 4 + r) * 128 + col] = acc[t][r];
    }
  }
}

// ---------------------------------------------------------------- MFMA fused MLP
__global__ __launch_bounds__(256) void k_mlp_m(float* __restrict__ h,
                                               const _Float16* __restrict__ W1t, const float* __restrict__ B1,
                                               const _Float16* __restrict__ W2t, const float* __restrict__ B2,
                                               const _Float16* __restrict__ W3t, const float* __restrict__ B3) {
  __shared__ _Float16 As[64 * 136];
  __shared__ _Float16 Bs[64 * 136];
  __shared__ _Float16 Ws[128 * 136];
  int tid = threadIdx.x;
  int r0 = blockIdx.x * 64;
  for (int j = tid; j < 2048; j += 256) {
    int row = j >> 5, c4 = (j & 31) * 4;
    float4 v = *(const float4*)(h + (size_t)(r0 + row) * 128 + c4);
    _Float16* d = &As[row * 136 + c4];
    d[0] = f2h(v.x); d[1] = f2h(v.y); d[2] = f2h(v.z); d[3] = f2h(v.w);
  }
  for (int j = tid; j < 4096; j += 256) {
    int row = j >> 5, c4 = (j & 31) * 4;
    *(ushort4*)&Ws[row * 136 + c4] = *(const ushort4*)(W1t + row * 128 + c4);
  }
  __syncthreads();
  int lane = tid & 63;
  int quad = lane >> 4, l16 = lane & 15;
  int wrow = (tid >> 6) * 16;
  f32x4 acc[8];

#pragma unroll
  for (int t = 0; t < 8; t++) acc[t] = (f32x4){0.f, 0.f, 0.f, 0.f};
#pragma unroll
  for (int kk = 0; kk < 4; kk++) {
    f16x8 a = *(const f16x8*)&As[(wrow + l16) * 136 + kk * 32 + quad * 8];
#pragma unroll
    for (int t = 0; t < 8; t++) {
      f16x8 b = *(const f16x8*)&Ws[(t * 16 + l16) * 136 + kk * 32 + quad * 8];
      acc[t] = __builtin_amdgcn_mfma_f32_16x16x32_f16(a, b, acc[t], 0, 0, 0);
    }
  }
#pragma unroll
  for (int t = 0; t < 8; t++) {
    int col = t * 16 + l16;
    float bv = B1[col];
#pragma unroll
    for (int r = 0; r < 4; r++)
      Bs[(wrow + quad * 4 + r) * 136 + col] = f2h(fmaxf(acc[t][r] + bv, 0.f));
  }
  __syncthreads();
  for (int j = tid; j < 4096; j += 256) {
    int row = j >> 5, c4 = (j & 31) * 4;
    *(ushort4*)&Ws[row * 136 + c4] = *(const ushort4*)(W2t + row * 128 + c4);
  }
  __syncthreads();

#pragma unroll
  for (int t = 0; t < 8; t++) acc[t] = (f32x4){0.f, 0.f, 0.f, 0.f};
#pragma unroll
  for (int kk = 0; kk < 4; kk++) {
    f16x8 a = *(const f16x8*)&Bs[(wrow + l16) * 136 + kk * 32 + quad * 8];
#pragma unroll
    for (int t = 0; t < 8; t++) {
      f16x8 b = *(const f16x8*)&Ws[(t * 16 + l16) * 136 + kk * 32 + quad * 8];
      acc[t] = __builtin_amdgcn_mfma_f32_16x16x32_f16(a, b, acc[t], 0, 0, 0);
    }
  }
#pragma unroll
  for (int t = 0; t < 8; t++) {
    int col = t * 16 + l16;
    float bv = B2[col];
#pragma unroll
    for (int r = 0; r < 4; r++)
      As[(wrow + quad * 4 + r) * 136 + col] = f2h(fmaxf(acc[t][r] + bv, 0.f));
  }
  __syncthreads();
  for (int j = tid; j < 4096; j += 256) {
    int row = j >> 5, c4 = (j & 31) * 4;
    *(ushort4*)&Ws[row * 136 + c4] = *(const ushort4*)(W3t + row * 128 + c4);
  }
  __syncthreads();

#pragma unroll
  for (int t = 0; t < 8; t++) acc[t] = (f32x4){0.f, 0.f, 0.f, 0.f};
#pragma unroll
  for (int kk = 0; kk < 4; kk++) {
    f16x8 a = *(const f16x8*)&As[(wrow + l16) * 136 + kk * 32 + quad * 8];
#pragma unroll
    for (int t = 0; t < 8; t++) {
      f16x8 b = *(const f16x8*)&Ws[(t * 16 + l16) * 136 + kk * 32 + quad * 8];
      acc[t] = __builtin_amdgcn_mfma_f32_16x16x32_f16(a, b, acc[t], 0, 0, 0);
    }
  }
#pragma unroll
  for (int t = 0; t < 8; t++) {
    int col = t * 16 + l16;
    float bv = B3[col];
#pragma unroll
    for (int r = 0; r < 4; r++) {
      size_t oo = (size_t)(r0 + wrow + quad * 4 + r) * 128 + col;
      h[oo] += acc[t][r] + bv;
    }
  }
}

// ---------------------------------------------------------------- attention, algebraically collapsed
// logit[n,h,k] = qs·hk[m] + sum_e edge[n,k,e]*qwk[n,e,h],  qwk[e,h] = sum_d qs[h,d]*Wk_e[e,h,d]
// o[n,h,:]    = sum_k p*hv[m] + sum_e pe[e,h]*Wv_e[e,:],   pe[e,h]  = sum_k p[k,h]*edge[n,k,e]
#define APW 8
__global__ __launch_bounds__(256) void k_attn(const float* __restrict__ q,
                                              const float* __restrict__ hk,
                                              const float* __restrict__ hv,
                                              const int* __restrict__ nbr,
                                              const float* __restrict__ edge,
                                              const float* __restrict__ wkb,
                                              const float* __restrict__ wvb,
                                              float* __restrict__ o) {
  __shared__ float wkbL[29 * 132];
  __shared__ float wvbL[29 * 132];
  __shared__ float eL[4][15 * 33];
  __shared__ float qL[4][128];
  __shared__ float qwkL[4][232];
  __shared__ float pL[4][120];
  __shared__ float peL[4][232];
  __shared__ int nbrL[4][16];
  int tid = threadIdx.x, wave = tid >> 6, lane = tid & 63;
  for (int j = tid; j < 29 * 128; j += 256) {
    int e = j >> 7, c = j & 127;
    wkbL[e * 132 + c] = wkb[j];
    wvbL[e * 132 + c] = wvb[j];
  }
  __syncthreads();
  float* el = eL[wave];
  float* ql = qL[wave];
  float* qwk = qwkL[wave];
  float* pl = pL[wave];
  float* pe = peL[wave];
  int* nbl = nbrL[wave];
  int h8 = lane & 7;       // head for P1/P2 lane mapping
  int k2 = lane >> 3;      // neighbor sub-index for P2
  int c2 = lane * 2;       // channel pair for P0/P5
  int h5 = lane >> 3;      // head of channel pair c2 (== c2>>4)
  int n0 = (blockIdx.x * 4 + wave) * APW;
#pragma unroll 1
  for (int ni = 0; ni < APW; ni++) {
    int n = n0 + ni;
    // ---- P0: stage edge, q (scaled), nbr into wave-private LDS
    const float* es = edge + (size_t)n * 435;
#pragma unroll
    for (int jj = 0; jj < 7; jj++) {
      int j = lane + jj * 64;
      if (j < 435) el[(j / 29) * 33 + (j % 29)] = es[j];
    }
    float2 q2 = *(const float2*)(q + (size_t)n * 128 + c2);
    q2.x *= 0.25f; q2.y *= 0.25f;
    *(float2*)&ql[c2] = q2;
    if (lane < 15) nbl[lane] = nbr[(size_t)n * 15 + lane];
    WSYNC();
    // ---- P1: q16 regs + qwk[e][h]
    float q16[16];
#pragma unroll
    for (int d = 0; d < 16; d++) q16[d] = ql[h8 * 16 + d];
#pragma unroll
    for (int p = 0; p < 4; p++) {
      int e = (p * 64 + lane) >> 3;
      if (e < 29) {
        const float* wrow = &wkbL[e * 132 + h8 * 16];
        float s = 0.f;
#pragma unroll
        for (int d = 0; d < 16; d++) s = fmaf(q16[d], wrow[d], s);
        qwk[e * 8 + h8] = s;
      }
    }
    WSYNC();
    // ---- P2: logits[k][h] -> pl
#pragma unroll
    for (int p = 0; p < 2; p++) {
      int k = p * 8 + k2;
      if (k < 15) {
        int m = nbl[k];
        const float* hkp = hk + (size_t)m * 128 + h8 * 16;
        float4 ha = *(const float4*)(hkp);
        float4 hb = *(const float4*)(hkp + 4);
        float4 hc = *(const float4*)(hkp + 8);
        float4 hd = *(const float4*)(hkp + 12);
        float dot = q16[0] * ha.x + q16[1] * ha.y + q16[2] * ha.z + q16[3] * ha.w
                  + q16[4] * hb.x + q16[5] * hb.y + q16[6] * hb.z + q16[7] * hb.w
                  + q16[8] * hc.x + q16[9] * hc.y + q16[10] * hc.z + q16[11] * hc.w
                  + q16[12] * hd.x + q16[13] * hd.y + q16[14] * hd.z + q16[15] * hd.w;
        float ep = 0.f;
#pragma unroll
        for (int e = 0; e < 29; e++) ep = fmaf(el[k * 33 + e], qwk[e * 8 + h8], ep);
        pl[k * 8 + h8] = dot + ep;
      }
    }
    WSYNC();
    // ---- P3: softmax per head (lanes 0..7), write normalized p
    if (lane < 8) {
      float mx = -1e30f;
#pragma unroll
      for (int k = 0; k < 15; k++) mx = fmaxf(mx, pl[k * 8 + lane]);
      float pv[15], s = 0.f;
#pragma unroll
      for (int k = 0; k < 15; k++) { pv[k] = __expf(pl[k * 8 + lane] - mx); s += pv[k]; }
      float inv = 1.f / s;
#pragma unroll
      for (int k = 0; k < 15; k++) pl[k * 8 + lane] = pv[k] * inv;
    }
    WSYNC();
    // ---- P4: pe[e][h]
#pragma unroll
    for (int p = 0; p < 4; p++) {
      int e = (p * 64 + lane) >> 3;
      if (e < 29) {
        float s = 0.f;
#pragma unroll
        for (int k = 0; k < 15; k++) s = fmaf(pl[k * 8 + h8], el[k * 33 + e], s);
        pe[e * 8 + h8] = s;
      }
    }
    WSYNC();
    // ---- P5: output channels
    float ox = 0.f, oy = 0.f;
#pragma unroll
    for (int k = 0; k < 15; k++) {
      int m = nbl[k];
      float2 hv2 = *(const float2*)(hv + (size_t)m * 128 + c2);
      float pk = pl[k * 8 + h5];
      ox = fmaf(pk, hv2.x, ox); oy = fmaf(pk, hv2.y, oy);
    }
#pragma unroll
    for (int e = 0; e < 29; e++) {
      float pv = pe[e * 8 + h5];
      float2 w2 = *(const float2*)(&wvbL[e * 132 + c2]);
      ox = fmaf(pv, w2.x, ox); oy = fmaf(pv, w2.y, oy);
    }
    *(float2*)(o + (size_t)n * 128 + c2) = make_float2(ox, oy);
    WSYNC();
  }
}

// ---------------------------------------------------------------- MFMA conv(k=3)+bias+leaky+residual+maxpool2
// x: (B,Tin,128) fp32 -> out: (B,Tin/2,128) fp32.  Wc: fp16 [kt][o][i]
__global__ __launch_bounds__(256) void k_convpool_m(const float* __restrict__ x,
                                                    const _Float16* __restrict__ Wc,
                                                    const float* __restrict__ bias,
                                                    float* __restrict__ outp, int Tin) {
  __shared__ _Float16 Xs[66 * 136];
  __shared__ _Float16 Ws[128 * 136];
  int tid = threadIdx.x;
  int b = blockIdx.y;
  int t0 = blockIdx.x * 64;
  // stage x rows t0-1 .. t0+64 as fp16
  for (int j = tid; j < 66 * 32; j += 256) {
    int row = j >> 5, c4 = (j & 31) * 4;
    int t = t0 - 1 + row;
    _Float16* d = &Xs[row * 136 + c4];
    if (t >= 0 && t < Tin) {
      float4 v = *(const float4*)(x + ((size_t)b * Tin + t) * 128 + c4);
      d[0] = f2h(v.x); d[1] = f2h(v.y); d[2] = f2h(v.z); d[3] = f2h(v.w);
    } else {
      d[0] = (_Float16)0.f; d[1] = (_Float16)0.f; d[2] = (_Float16)0.f; d[3] = (_Float16)0.f;
    }
  }
  int lane = tid & 63;
  int quad = lane >> 4, l16 = lane & 15;
  int wrow = (tid >> 6) * 16;
  f32x4 acc[8];
#pragma unroll
  for (int t = 0; t < 8; t++) acc[t] = (f32x4){0.f, 0.f, 0.f, 0.f};
  for (int kt = 0; kt < 3; kt++) {
    __syncthreads();
    const _Float16* Wt = Wc + (size_t)kt * 16384;
    for (int j = tid; j < 4096; j += 256) {
      int row = j >> 5, c4 = (j & 31) * 4;
      *(ushort4*)&Ws[row * 136 + c4] = *(const ushort4*)(Wt + row * 128 + c4);
    }
    __syncthreads();
#pragma unroll
    for (int kk = 0; kk < 4; kk++) {
      f16x8 a = *(const f16x8*)&Xs[(wrow + l16 + kt) * 136 + kk * 32 + quad * 8];
#pragma unroll
      for (int t = 0; t < 8; t++) {
        f16x8 bfr = *(const f16x8*)&Ws[(t * 16 + l16) * 136 + kk * 32 + quad * 8];
        acc[t] = __builtin_amdgcn_mfma_f32_16x16x32_f16(a, bfr, acc[t], 0, 0, 0);
      }
    }
  }
  int Tout = Tin >> 1;
#pragma unroll
  for (int t = 0; t < 8; t++) {
    int col = t * 16 + l16;
    float bv = bias[col];
#pragma unroll
    for (int rp = 0; rp < 2; rp++) {
      int rl0 = wrow + quad * 4 + rp * 2;
      float y0 = acc[t][rp * 2] + bv;
      float y1 = acc[t][rp * 2 + 1] + bv;
      float z0 = (float)Xs[(rl0 + 1) * 136 + col] + (y0 >= 0.f ? y0 : 0.01f * y0);
      float z1 = (float)Xs[(rl0 + 2) * 136 + col] + (y1 >= 0.f ? y1 : 0.01f * y1);
      outp[((size_t)b * Tout + ((t0 + rl0) >> 1)) * 128 + col] = fmaxf(z0, z1);
    }
  }
}

// ---------------------------------------------------------------- final reduce
__global__ __launch_bounds__(128) void k_final(const float* __restrict__ x,
                                               const float* __restrict__ ew,
                                               const float* __restrict__ ebb,
                                               float* __restrict__ outp) {
  int b = blockIdx.x, cc = threadIdx.x;
  float s = 0.f;
#pragma unroll
  for (int t = 0; t < 32; t++) s += x[((size_t)b * 32 + t) * 128 + cc];
  float v = s * ew[cc];
#pragma unroll
  for (int m = 1; m < 64; m <<= 1) v += __shfl_xor(v, m);
  __shared__ float red[2];
  if ((cc & 63) == 0) red[cc >> 6] = v;
  __syncthreads();
  if (cc == 0) outp[b] = red[0] + red[1] + ebb[0];
}

// ---------------------------------------------------------------- launch
extern "C" void kernel_launch(void* const* d_in, const int* in_sizes, int n_in,
                              void* d_out, int out_size, void* d_ws, size_t ws_size,
                              hipStream_t stream) {
  (void)in_sizes; (void)n_in; (void)out_size; (void)ws_size;
  const float* tert    = (const float*)d_in[0];
  const float* noise   = (const float*)d_in[3];
  const float* embed_w = (const float*)d_in[4];
  const float* embed_b = (const float*)d_in[5];
  const float* wq = (const float*)d_in[6];
  const float* wk = (const float*)d_in[7];
  const float* wv = (const float*)d_in[8];
  const float* wo = (const float*)d_in[9];
  const float* w1 = (const float*)d_in[10];
  const float* b1 = (const float*)d_in[11];
  const float* w2 = (const float*)d_in[12];
  const float* b2 = (const float*)d_in[13];
  const float* w3 = (const float*)d_in[14];
  const float* b3 = (const float*)d_in[15];
  const float* pw = (const float*)d_in[16];
  const float* pb = (const float*)d_in[17];
  const float* ew = (const float*)d_in[18];
  const float* eb = (const float*)d_in[19];
  float* outp = (float*)d_out;

  float* ws = (float*)d_ws;
  size_t off = 0;
  float* pos  = ws + off; off += 98304;
  float* R    = ws + off; off += 294912;
  int*   nbr  = (int*)(ws + off); off += 491520;
  float* edge = ws + off; off += 14254080;
  float* h    = ws + off; off += 4194304;
  float* q    = ws + off; off += 4194304;
  float* hk   = ws + off; off += 4194304;
  float* hv   = ws + off; off += 4194304;
  float* o    = ws + off; off += 4194304;
  float* xa   = ws + off; off += 2097152;
  float* xb   = ws + off; off += 1048576;
  _Float16* wbt = (_Float16*)(ws + off); off += 172032;  // 3*7*16384 fp16
  _Float16* wct = (_Float16*)(ws + off); off += 98304;   // 4*3*128*128 fp16

  k_frames<<<128, 256, 0, stream>>>(tert, pos, R);
  k_knn<<<8192, 256, 0, stream>>>(pos, noise, nbr);
  k_edge<<<1920, 256, 0, stream>>>(pos, R, nbr, edge);
  k_hinit<<<512, 256, 0, stream>>>(embed_w, embed_b, h);
  k_prepw<<<1344, 256, 0, stream>>>(wq, wk, wv, wo, w1, w2, w3, wbt);
  k_prepcw<<<768, 256, 0, stream>>>(pw, wct);

  for (int l = 0; l < 3; l++) {
    const _Float16* wtq = wbt + (size_t)(l * 7 + 0) * 16384;
    const _Float16* wtk = wbt + (size_t)(l * 7 + 1) * 16384;
    const _Float16* wtv = wbt + (size_t)(l * 7 + 2) * 16384;
    const _Float16* wto = wbt + (size_t)(l * 7 + 3) * 16384;
    const _Float16* wt1 = wbt + (size_t)(l * 7 + 4) * 16384;
    const _Float16* wt2 = wbt + (size_t)(l * 7 + 5) * 16384;
    const _Float16* wt3 = wbt + (size_t)(l * 7 + 6) * 16384;
    const float* wk_l = wk + (size_t)l * 157 * 128;
    const float* wv_l = wv + (size_t)l * 157 * 128;

    k_gemm3m<<<512, 256, 0, stream>>>(h, wtq, wtk, wtv, q, hk, hv);
    k_attn<<<1024, 256, 0, stream>>>(q, hk, hv, nbr, edge,
                                     wk_l + 128 * 128, wv_l + 128 * 128, o);
    k_gemm_m<<<512, 256, 0, stream>>>(o, wto, nullptr, h, h, 0);
    k_mlp_m<<<512, 256, 0, stream>>>(h, wt1, b1 + l * 128, wt2, b2 + l * 128,
                                     wt3, b3 + l * 128);
  }

  k_convpool_m<<<dim3(8, 64), 256, 0, stream>>>(h,  wct + 0 * 49152, pb + 0,   xa, 512);
  k_convpool_m<<<dim3(4, 64), 256, 0, stream>>>(xa, wct + 1 * 49152, pb + 128, xb, 256);
  k_convpool_m<<<dim3(2, 64), 256, 0, stream>>>(xb, wct + 2 * 49152, pb + 256, xa, 128);
  k_convpool_m<<<dim3(1, 64), 256, 0, stream>>>(xa, wct + 3 * 49152, pb + 384, xb, 64);
  k_final<<<64, 128, 0, stream>>>(xb, ew, eb, outp);
}

// Round 4
// 645.424 us; speedup vs baseline: 2.4858x; 1.3178x over previous
//
#include <hip/hip_runtime.h>
#include <math.h>

#define N_TOT 32768
#define NNBR 15
#define EDGEF 29
#define APW 8

typedef __attribute__((ext_vector_type(8))) _Float16 f16x8;
typedef __attribute__((ext_vector_type(2))) _Float16 f16x2;
typedef __attribute__((ext_vector_type(4))) float f32x4;

#define CBAR() __asm__ volatile("" ::: "memory")

__device__ __forceinline__ _Float16 f2h(float x) { return (_Float16)x; }

// ---------------------------------------------------------------- frames
__global__ __launch_bounds__(256) void k_frames(const float* __restrict__ tert,
                                                float* __restrict__ pos,
                                                float* __restrict__ R) {
  int n = blockIdx.x * 256 + threadIdx.x;
  if (n >= N_TOT) return;
  float px = tert[n * 9 + 3], py = tert[n * 9 + 4], pz = tert[n * 9 + 5];
  pos[n * 3 + 0] = px; pos[n * 3 + 1] = py; pos[n * 3 + 2] = pz;

  int i0 = (n > 0) ? (n - 1) : 0;
  int i1 = (n < N_TOT - 1) ? n : (N_TOT - 2);

  float ax = tert[(i0 + 1) * 9 + 3] - tert[i0 * 9 + 3];
  float ay = tert[(i0 + 1) * 9 + 4] - tert[i0 * 9 + 4];
  float az = tert[(i0 + 1) * 9 + 5] - tert[i0 * 9 + 5];
  float il = 1.f / (sqrtf(ax * ax + ay * ay + az * az) + 1e-8f);
  float ux = ax * il, uy = ay * il, uz = az * il;

  float cx = tert[(i1 + 1) * 9 + 3] - tert[i1 * 9 + 3];
  float cy = tert[(i1 + 1) * 9 + 4] - tert[i1 * 9 + 4];
  float cz = tert[(i1 + 1) * 9 + 5] - tert[i1 * 9 + 5];
  il = 1.f / (sqrtf(cx * cx + cy * cy + cz * cz) + 1e-8f);
  float vx = cx * il, vy = cy * il, vz = cz * il;

  float bx = ux - vx, by = uy - vy, bz = uz - vz;
  il = 1.f / (sqrtf(bx * bx + by * by + bz * bz) + 1e-8f);
  bx *= il; by *= il; bz *= il;

  float nx = uy * vz - uz * vy;
  float ny = uz * vx - ux * vz;
  float nz = ux * vy - uy * vx;
  il = 1.f / (sqrtf(nx * nx + ny * ny + nz * nz) + 1e-8f);
  nx *= il; ny *= il; nz *= il;

  float ex = by * nz - bz * ny;
  float ey = bz * nx - bx * nz;
  float ez = bx * ny - by * nx;

  float* Rn = R + (size_t)n * 9;
  Rn[0] = bx; Rn[1] = nx; Rn[2] = ex;
  Rn[3] = by; Rn[4] = ny; Rn[5] = ey;
  Rn[6] = bz; Rn[7] = nz; Rn[8] = ez;
}

// ---------------------------------------------------------------- kNN, packed 64-bit keys
__global__ __launch_bounds__(256) void k_knn(const float* __restrict__ pos,
                                             const float* __restrict__ noise,
                                             int* __restrict__ nbr) {
  int wave = threadIdx.x >> 6, lane = threadIdx.x & 63;
  int row = blockIdx.x * 4 + wave;
  int b = row >> 9;
  float pix = pos[row * 3 + 0], piy = pos[row * 3 + 1], piz = pos[row * 3 + 2];
  const float* nrow = noise + (size_t)row * 512;
  const float* pb = pos + (size_t)b * 512 * 3;
  unsigned long long key[8];
#pragma unroll
  for (int jj = 0; jj < 8; jj++) {
    int j = lane + jj * 64;
    float dx = pb[j * 3 + 0] - pix;
    float dy = pb[j * 3 + 1] - piy;
    float dz = pb[j * 3 + 2] - piz;
    float c = -sqrtf(dx * dx + dy * dy + dz * dz) + 3.f * nrow[j];
    unsigned u = __float_as_uint(c);
    unsigned s = u ^ (unsigned)(((int)u >> 31) | (int)0x80000000);
    key[jj] = ((unsigned long long)s << 9) | (unsigned)(511 - j);
  }
  unsigned long long best = key[0];
#pragma unroll
  for (int jj = 1; jj < 8; jj++) best = key[jj] > best ? key[jj] : best;
  int jmine = 0;
#pragma unroll 1
  for (int it = 0; it < NNBR; it++) {
    unsigned long long g = best;
#pragma unroll
    for (int m = 1; m < 64; m <<= 1) {
      unsigned long long og = __shfl_xor(g, m);
      g = og > g ? og : g;
    }
    int j = 511 - (int)(g & 511ull);
    if (lane == it) jmine = j;
    if ((j & 63) == lane) {
      int slot = j >> 6;
#pragma unroll
      for (int jj = 0; jj < 8; jj++) if (slot == jj) key[jj] = 0ull;
      best = key[0];
#pragma unroll
      for (int jj = 1; jj < 8; jj++) best = key[jj] > best ? key[jj] : best;
    }
  }
  if (lane < NNBR) nbr[(size_t)row * NNBR + lane] = b * 512 + jmine;
}

// ---------------------------------------------------------------- edge features (fp16 out)
__global__ __launch_bounds__(256) void k_edge(const float* __restrict__ pos,
                                              const float* __restrict__ R,
                                              const int* __restrict__ nbr,
                                              _Float16* __restrict__ edge) {
  int idx = blockIdx.x * 256 + threadIdx.x;
  if (idx >= N_TOT * NNBR) return;
  int n = idx / NNBR;
  int m = nbr[idx];
  float dx = pos[m * 3 + 0] - pos[n * 3 + 0];
  float dy = pos[m * 3 + 1] - pos[n * 3 + 1];
  float dz = pos[m * 3 + 2] - pos[n * 3 + 2];
  float d = sqrtf(dx * dx + dy * dy + dz * dz);
  _Float16* e = edge + (size_t)idx * EDGEF;
#pragma unroll
  for (int j = 0; j < 16; j++) {
    float mu = (20.f / 15.f) * (float)j;
    float t = (d - mu) * 0.8f;
    e[j] = f2h(__expf(-t * t));
  }
  float inv = 1.f / (d + 1e-8f);
  float ux = dx * inv, uy = dy * inv, uz = dz * inv;
  float Rn[9], Rm[9];
#pragma unroll
  for (int j = 0; j < 9; j++) { Rn[j] = R[(size_t)n * 9 + j]; Rm[j] = R[(size_t)m * 9 + j]; }
#pragma unroll
  for (int cc = 0; cc < 3; cc++)
    e[16 + cc] = f2h(Rn[0 * 3 + cc] * ux + Rn[1 * 3 + cc] * uy + Rn[2 * 3 + cc] * uz);
#pragma unroll
  for (int cc = 0; cc < 3; cc++)
#pragma unroll
    for (int dd = 0; dd < 3; dd++)
      e[19 + cc * 3 + dd] = f2h(Rn[0 * 3 + cc] * Rm[0 * 3 + dd] +
                                Rn[1 * 3 + cc] * Rm[1 * 3 + dd] +
                                Rn[2 * 3 + cc] * Rm[2 * 3 + dd]);
  e[28] = f2h((float)(m - n));
}

// ---------------------------------------------------------------- h init (fp16)
__global__ __launch_bounds__(256) void k_hinit(const float* __restrict__ ew,
                                               const float* __restrict__ ebias,
                                               _Float16* __restrict__ h) {
  __shared__ float hv[128];
  int tid = threadIdx.x;
  if (tid < 128) {
    float s = ebias[tid];
#pragma unroll
    for (int i = 0; i < 27; i++) s += ew[i * 128 + tid];
    hv[tid] = s;
  }
  __syncthreads();
  size_t total = (size_t)N_TOT * 128;
  for (size_t j = (size_t)blockIdx.x * 256 + tid; j < total; j += (size_t)gridDim.x * 256)
    h[j] = f2h(hv[j & 127]);
}

// ---------------------------------------------------------------- dense weight prep: fp32 [k][n] -> fp16 [n][k]
__global__ __launch_bounds__(256) void k_prepw(const float* __restrict__ wq, const float* __restrict__ wk,
                                               const float* __restrict__ wv, const float* __restrict__ wo,
                                               const float* __restrict__ w1, const float* __restrict__ w2,
                                               const float* __restrict__ w3, _Float16* __restrict__ wbt) {
  int idx = blockIdx.x * 256 + threadIdx.x;
  if (idx >= 3 * 7 * 16384) return;
  int l = idx / (7 * 16384);
  int r = idx % (7 * 16384);
  int w = r / 16384;
  int e = r % 16384;
  int k = e >> 7, n = e & 127;
  float val;
  switch (w) {
    case 0: val = wq[(size_t)l * 16384 + e]; break;
    case 1: val = wk[(size_t)l * 157 * 128 + e]; break;
    case 2: val = wv[(size_t)l * 157 * 128 + e]; break;
    case 3: val = wo[(size_t)l * 16384 + e]; break;
    case 4: val = w1[(size_t)l * 16384 + e]; break;
    case 5: val = w2[(size_t)l * 16384 + e]; break;
    default: val = w3[(size_t)l * 16384 + e]; break;
  }
  wbt[(size_t)(l * 7 + w) * 16384 + n * 128 + k] = f2h(val);
}

// ---------------------------------------------------------------- conv weight prep
__global__ __launch_bounds__(256) void k_prepcw(const float* __restrict__ pw, _Float16* __restrict__ wc) {
  int idx = blockIdx.x * 256 + threadIdx.x;
  if (idx >= 4 * 128 * 128 * 3) return;
  int kt = idx % 3;
  int rest = idx / 3;
  int i = rest % 128; rest /= 128;
  int oo = rest % 128;
  int s = rest / 128;
  wc[(((size_t)s * 3 + kt) * 128 + oo) * 128 + i] = f2h(pw[idx]);
}

// ---------------------------------------------------------------- shared GEMM helpers
__device__ __forceinline__ void stage_w(const _Float16* __restrict__ W, _Float16* Ws, int tid) {
  for (int j = tid; j < 2048; j += 256) {
    int row = j >> 4, seg = (j & 15) * 8;
    *(uint4*)&Ws[row * 136 + seg] = *(const uint4*)(W + (size_t)row * 128 + seg);
  }
}
__device__ __forceinline__ void gemm_tile(const _Float16* X, const _Float16* Ws,
                                          int wrow, int l16, int quad, f32x4 acc[8]) {
#pragma unroll
  for (int t = 0; t < 8; t++) acc[t] = (f32x4){0.f, 0.f, 0.f, 0.f};
#pragma unroll
  for (int kk = 0; kk < 4; kk++) {
    f16x8 a = *(const f16x8*)&X[(wrow + l16) * 136 + kk * 32 + quad * 8];
#pragma unroll
    for (int t = 0; t < 8; t++) {
      f16x8 b = *(const f16x8*)&Ws[(t * 16 + l16) * 136 + kk * 32 + quad * 8];
      acc[t] = __builtin_amdgcn_mfma_f32_16x16x32_f16(a, b, acc[t], 0, 0, 0);
    }
  }
}

// ---------------------------------------------------------------- layer-0 QKV
__global__ __launch_bounds__(256) void k_qkv(const _Float16* __restrict__ A,
                                             const _Float16* __restrict__ Wqt,
                                             const _Float16* __restrict__ Wkt,
                                             const _Float16* __restrict__ Wvt,
                                             _Float16* __restrict__ q, _Float16* __restrict__ hk,
                                             _Float16* __restrict__ hv) {
  __shared__ _Float16 X[64 * 136];
  __shared__ _Float16 Ws[128 * 136];
  int tid = threadIdx.x, r0 = blockIdx.x * 64;
  int lane = tid & 63, quad = lane >> 4, l16 = lane & 15, wrow = (tid >> 6) * 16;
  for (int j = tid; j < 1024; j += 256) {
    int row = j >> 4, seg = (j & 15) * 8;
    *(uint4*)&X[row * 136 + seg] = *(const uint4*)(A + (size_t)(r0 + row) * 128 + seg);
  }
  const _Float16* wts[3] = {Wqt, Wkt, Wvt};
  _Float16* cs[3] = {q, hk, hv};
  f32x4 acc[8];
  for (int w = 0; w < 3; w++) {
    __syncthreads();
    stage_w(wts[w], Ws, tid);
    __syncthreads();
    gemm_tile(X, Ws, wrow, l16, quad, acc);
    _Float16* C = cs[w];
#pragma unroll
    for (int t = 0; t < 8; t++) {
      int col = t * 16 + l16;
#pragma unroll
      for (int r = 0; r < 4; r++)
        C[(size_t)(r0 + wrow + quad * 4 + r) * 128 + col] = f2h(acc[t][r]);
    }
  }
}

// ---------------------------------------------------------------- fused o-proj + residual + MLP (+ next QKV)
__global__ __launch_bounds__(256) void k_post(const _Float16* __restrict__ o,
                                              _Float16* __restrict__ h,
                                              const _Float16* __restrict__ Wot,
                                              const _Float16* __restrict__ W1t, const float* __restrict__ B1,
                                              const _Float16* __restrict__ W2t, const float* __restrict__ B2,
                                              const _Float16* __restrict__ W3t, const float* __restrict__ B3,
                                              const _Float16* __restrict__ Wqt,
                                              const _Float16* __restrict__ Wkt,
                                              const _Float16* __restrict__ Wvt,
                                              _Float16* __restrict__ qo, _Float16* __restrict__ hko,
                                              _Float16* __restrict__ hvo, int do_qkv) {
  __shared__ _Float16 X[64 * 136];
  __shared__ _Float16 Ws[128 * 136];
  int tid = threadIdx.x, r0 = blockIdx.x * 64;
  int lane = tid & 63, quad = lane >> 4, l16 = lane & 15, wrow = (tid >> 6) * 16;
  for (int j = tid; j < 1024; j += 256) {
    int row = j >> 4, seg = (j & 15) * 8;
    *(uint4*)&X[row * 136 + seg] = *(const uint4*)(o + (size_t)(r0 + row) * 128 + seg);
  }
  stage_w(Wot, Ws, tid);
  __syncthreads();
  f32x4 acc[8], hres[8];
  gemm_tile(X, Ws, wrow, l16, quad, acc);
#pragma unroll
  for (int t = 0; t < 8; t++) {
    int col = t * 16 + l16;
#pragma unroll
    for (int r = 0; r < 4; r++)
      hres[t][r] = acc[t][r] + (float)h[(size_t)(r0 + wrow + quad * 4 + r) * 128 + col];
  }
  __syncthreads();
#pragma unroll
  for (int t = 0; t < 8; t++) {
    int col = t * 16 + l16;
#pragma unroll
    for (int r = 0; r < 4; r++)
      X[(wrow + quad * 4 + r) * 136 + col] = f2h(hres[t][r]);
  }
  stage_w(W1t, Ws, tid);
  __syncthreads();
  gemm_tile(X, Ws, wrow, l16, quad, acc);
  __syncthreads();
#pragma unroll
  for (int t = 0; t < 8; t++) {
    int col = t * 16 + l16; float bv = B1[col];
#pragma unroll
    for (int r = 0; r < 4; r++)
      X[(wrow + quad * 4 + r) * 136 + col] = f2h(fmaxf(acc[t][r] + bv, 0.f));
  }
  stage_w(W2t, Ws, tid);
  __syncthreads();
  gemm_tile(X, Ws, wrow, l16, quad, acc);
  __syncthreads();
#pragma unroll
  for (int t = 0; t < 8; t++) {
    int col = t * 16 + l16; float bv = B2[col];
#pragma unroll
    for (int r = 0; r < 4; r++)
      X[(wrow + quad * 4 + r) * 136 + col] = f2h(fmaxf(acc[t][r] + bv, 0.f));
  }
  stage_w(W3t, Ws, tid);
  __syncthreads();
  gemm_tile(X, Ws, wrow, l16, quad, acc);
  __syncthreads();
#pragma unroll
  for (int t = 0; t < 8; t++) {
    int col = t * 16 + l16; float bv = B3[col];
#pragma unroll
    for (int r = 0; r < 4; r++) {
      float v = hres[t][r] + acc[t][r] + bv;
      h[(size_t)(r0 + wrow + quad * 4 + r) * 128 + col] = f2h(v);
      if (do_qkv) X[(wrow + quad * 4 + r) * 136 + col] = f2h(v);
    }
  }
  if (!do_qkv) return;
  const _Float16* wts[3] = {Wqt, Wkt, Wvt};
  _Float16* cs[3] = {qo, hko, hvo};
  for (int w = 0; w < 3; w++) {
    __syncthreads();
    stage_w(wts[w], Ws, tid);
    __syncthreads();
    gemm_tile(X, Ws, wrow, l16, quad, acc);
    _Float16* C = cs[w];
#pragma unroll
    for (int t = 0; t < 8; t++) {
      int col = t * 16 + l16;
#pragma unroll
      for (int r = 0; r < 4; r++)
        C[(size_t)(r0 + wrow + quad * 4 + r) * 128 + col] = f2h(acc[t][r]);
    }
  }
}

// ---------------------------------------------------------------- attention (collapsed, wave-sync via in-order DS)
__global__ __launch_bounds__(256) void k_attn(const _Float16* __restrict__ q,
                                              const _Float16* __restrict__ hk,
                                              const _Float16* __restrict__ hv,
                                              const int* __restrict__ nbr,
                                              const _Float16* __restrict__ edge,
                                              const float* __restrict__ wkb,
                                              const float* __restrict__ wvb,
                                              _Float16* __restrict__ o) {
  __shared__ float wkbL[29 * 132];
  __shared__ float wvbL[29 * 132];
  __shared__ float eL[4][15 * 33];
  __shared__ float qwkL[4][232];
  __shared__ float pL[4][120];
  __shared__ float peL[4][232];
  __shared__ int nbrL[4][16];
  int tid = threadIdx.x, wave = tid >> 6, lane = tid & 63;
  for (int j = tid; j < 29 * 128; j += 256) {
    int e = j >> 7, c = j & 127;
    wkbL[e * 132 + c] = wkb[j];
    wvbL[e * 132 + c] = wvb[j];
  }
  __syncthreads();
  float* el = eL[wave];
  float* qwk = qwkL[wave];
  float* pl = pL[wave];
  float* pe = peL[wave];
  int* nbl = nbrL[wave];
  int h8 = lane & 7, k2 = lane >> 3, c2 = lane * 2, h5 = lane >> 3;
  int n0 = (blockIdx.x * 4 + wave) * APW;
#pragma unroll 1
  for (int ni = 0; ni < APW; ni++) {
    int n = n0 + ni;
    // P0: stage edge (fp16->fp32) and nbr; load q from global
    const _Float16* es = edge + (size_t)n * 435;
#pragma unroll
    for (int jj = 0; jj < 7; jj++) {
      int j = lane + jj * 64;
      if (j < 435) el[(j / 29) * 33 + (j % 29)] = (float)es[j];
    }
    if (lane < 15) nbl[lane] = nbr[(size_t)n * NNBR + lane];
    const _Float16* qp = q + (size_t)n * 128 + h8 * 16;
    f16x8 qa = *(const f16x8*)qp;
    f16x8 qb = *(const f16x8*)(qp + 8);
    float q16[16];
#pragma unroll
    for (int d = 0; d < 8; d++) { q16[d] = 0.25f * (float)qa[d]; q16[8 + d] = 0.25f * (float)qb[d]; }
    CBAR();
    // P1: qwk[e][h]
#pragma unroll
    for (int p = 0; p < 4; p++) {
      int e = (p * 64 + lane) >> 3;
      if (e < 29) {
        const float* wrow = &wkbL[e * 132 + h8 * 16];
        float s = 0.f;
#pragma unroll
        for (int d = 0; d < 16; d++) s = fmaf(q16[d], wrow[d], s);
        qwk[e * 8 + h8] = s;
      }
    }
    CBAR();
    // P2: logits
#pragma unroll
    for (int p = 0; p < 2; p++) {
      int k = p * 8 + k2;
      if (k < 15) {
        int m = nbl[k];
        const _Float16* hkp = hk + (size_t)m * 128 + h8 * 16;
        f16x8 ha = *(const f16x8*)hkp;
        f16x8 hb = *(const f16x8*)(hkp + 8);
        float dot = 0.f;
#pragma unroll
        for (int d = 0; d < 8; d++) dot = fmaf(q16[d], (float)ha[d], dot);
#pragma unroll
        for (int d = 0; d < 8; d++) dot = fmaf(q16[8 + d], (float)hb[d], dot);
        float ep = 0.f;
#pragma unroll
        for (int e = 0; e < 29; e++) ep = fmaf(el[k * 33 + e], qwk[e * 8 + h8], ep);
        pl[k * 8 + h8] = dot + ep;
      }
    }
    CBAR();
    // P3: softmax per head
    if (lane < 8) {
      float mx = -1e30f;
#pragma unroll
      for (int k = 0; k < 15; k++) mx = fmaxf(mx, pl[k * 8 + lane]);
      float pv[15], s = 0.f;
#pragma unroll
      for (int k = 0; k < 15; k++) { pv[k] = __expf(pl[k * 8 + lane] - mx); s += pv[k]; }
      float inv = 1.f / s;
#pragma unroll
      for (int k = 0; k < 15; k++) pl[k * 8 + lane] = pv[k] * inv;
    }
    CBAR();
    // P4: pe[e][h]
#pragma unroll
    for (int p = 0; p < 4; p++) {
      int e = (p * 64 + lane) >> 3;
      if (e < 29) {
        float s = 0.f;
#pragma unroll
        for (int k = 0; k < 15; k++) s = fmaf(pl[k * 8 + h8], el[k * 33 + e], s);
        pe[e * 8 + h8] = s;
      }
    }
    CBAR();
    // P5: output channels
    float ox = 0.f, oy = 0.f;
#pragma unroll
    for (int k = 0; k < 15; k++) {
      int m = nbl[k];
      f16x2 hh = *(const f16x2*)(hv + (size_t)m * 128 + c2);
      float pk = pl[k * 8 + h5];
      ox = fmaf(pk, (float)hh.x, ox);
      oy = fmaf(pk, (float)hh.y, oy);
    }
#pragma unroll
    for (int e = 0; e < 29; e++) {
      float pv2 = pe[e * 8 + h5];
      ox = fmaf(pv2, wvbL[e * 132 + c2], ox);
      oy = fmaf(pv2, wvbL[e * 132 + c2 + 1], oy);
    }
    f16x2 o2 = {f2h(ox), f2h(oy)};
    *(f16x2*)(o + (size_t)n * 128 + c2) = o2;
    CBAR();
  }
}

// ---------------------------------------------------------------- MFMA conv+leaky+residual+maxpool2 (fp16 I/O)
__global__ __launch_bounds__(256) void k_convpool_m(const _Float16* __restrict__ x,
                                                    const _Float16* __restrict__ Wc,
                                                    const float* __restrict__ bias,
                                                    _Float16* __restrict__ outp, int Tin) {
  __shared__ _Float16 Xs[66 * 136];
  __shared__ _Float16 Ws[128 * 136];
  int tid = threadIdx.x;
  int b = blockIdx.y;
  int t0 = blockIdx.x * 64;
  for (int j = tid; j < 66 * 16; j += 256) {
    int row = j >> 4, seg = (j & 15) * 8;
    int t = t0 - 1 + row;
    uint4 v = {0u, 0u, 0u, 0u};
    if (t >= 0 && t < Tin) v = *(const uint4*)(x + ((size_t)b * Tin + t) * 128 + seg);
    *(uint4*)&Xs[row * 136 + seg] = v;
  }
  int lane = tid & 63, quad = lane >> 4, l16 = lane & 15, wrow = (tid >> 6) * 16;
  f32x4 acc[8];
#pragma unroll
  for (int t = 0; t < 8; t++) acc[t] = (f32x4){0.f, 0.f, 0.f, 0.f};
  for (int kt = 0; kt < 3; kt++) {
    __syncthreads();
    stage_w(Wc + (size_t)kt * 16384, Ws, tid);
    __syncthreads();
#pragma unroll
    for (int kk = 0; kk < 4; kk++) {
      f16x8 a = *(const f16x8*)&Xs[(wrow + l16 + kt) * 136 + kk * 32 + quad * 8];
#pragma unroll
      for (int t = 0; t < 8; t++) {
        f16x8 bfr = *(const f16x8*)&Ws[(t * 16 + l16) * 136 + kk * 32 + quad * 8];
        acc[t] = __builtin_amdgcn_mfma_f32_16x16x32_f16(a, bfr, acc[t], 0, 0, 0);
      }
    }
  }
  int Tout = Tin >> 1;
#pragma unroll
  for (int t = 0; t < 8; t++) {
    int col = t * 16 + l16;
    float bv = bias[col];
#pragma unroll
    for (int rp = 0; rp < 2; rp++) {
      int rl0 = wrow + quad * 4 + rp * 2;
      float y0 = acc[t][rp * 2] + bv;
      float y1 = acc[t][rp * 2 + 1] + bv;
      float z0 = (float)Xs[(rl0 + 1) * 136 + col] + (y0 >= 0.f ? y0 : 0.01f * y0);
      float z1 = (float)Xs[(rl0 + 2) * 136 + col] + (y1 >= 0.f ? y1 : 0.01f * y1);
      outp[((size_t)b * Tout + ((t0 + rl0) >> 1)) * 128 + col] = f2h(fmaxf(z0, z1));
    }
  }
}

// ---------------------------------------------------------------- final reduce
__global__ __launch_bounds__(128) void k_final(const _Float16* __restrict__ x,
                                               const float* __restrict__ ew,
                                               const float* __restrict__ ebb,
                                               float* __restrict__ outp) {
  int b = blockIdx.x, cc = threadIdx.x;
  float s = 0.f;
#pragma unroll
  for (int t = 0; t < 32; t++) s += (float)x[((size_t)b * 32 + t) * 128 + cc];
  float v = s * ew[cc];
#pragma unroll
  for (int m = 1; m < 64; m <<= 1) v += __shfl_xor(v, m);
  __shared__ float red[2];
  if ((cc & 63) == 0) red[cc >> 6] = v;
  __syncthreads();
  if (cc == 0) outp[b] = red[0] + red[1] + ebb[0];
}

// ---------------------------------------------------------------- launch
extern "C" void kernel_launch(void* const* d_in, const int* in_sizes, int n_in,
                              void* d_out, int out_size, void* d_ws, size_t ws_size,
                              hipStream_t stream) {
  (void)in_sizes; (void)n_in; (void)out_size; (void)ws_size;
  const float* tert    = (const float*)d_in[0];
  const float* noise   = (const float*)d_in[3];
  const float* embed_w = (const float*)d_in[4];
  const float* embed_b = (const float*)d_in[5];
  const float* wq = (const float*)d_in[6];
  const float* wk = (const float*)d_in[7];
  const float* wv = (const float*)d_in[8];
  const float* wo = (const float*)d_in[9];
  const float* w1 = (const float*)d_in[10];
  const float* b1 = (const float*)d_in[11];
  const float* w2 = (const float*)d_in[12];
  const float* b2 = (const float*)d_in[13];
  const float* w3 = (const float*)d_in[14];
  const float* b3 = (const float*)d_in[15];
  const float* pw = (const float*)d_in[16];
  const float* pb = (const float*)d_in[17];
  const float* ew = (const float*)d_in[18];
  const float* eb = (const float*)d_in[19];
  float* outp = (float*)d_out;

  char* W = (char*)d_ws;
  float* pos  = (float*)W;        W += 393216;     // N*3 f32
  float* R    = (float*)W;        W += 1179648;    // N*9 f32
  int*   nbr  = (int*)W;          W += 1966080;    // N*15 i32
  _Float16* edge = (_Float16*)W;  W += 28508160;   // N*435 f16
  _Float16* h    = (_Float16*)W;  W += 8388608;    // N*128 f16
  _Float16* q    = (_Float16*)W;  W += 8388608;
  _Float16* hk   = (_Float16*)W;  W += 8388608;
  _Float16* hv   = (_Float16*)W;  W += 8388608;
  _Float16* o    = (_Float16*)W;  W += 8388608;
  _Float16* xa   = (_Float16*)W;  W += 4194304;    // B*256*128 f16
  _Float16* xb   = (_Float16*)W;  W += 2097152;    // B*128*128 f16
  _Float16* wbt  = (_Float16*)W;  W += 688128;     // 21*16384 f16
  _Float16* wct  = (_Float16*)W;  W += 393216;     // 12*16384 f16

  k_frames<<<128, 256, 0, stream>>>(tert, pos, R);
  k_knn<<<8192, 256, 0, stream>>>(pos, noise, nbr);
  k_edge<<<1920, 256, 0, stream>>>(pos, R, nbr, edge);
  k_hinit<<<512, 256, 0, stream>>>(embed_w, embed_b, h);
  k_prepw<<<1344, 256, 0, stream>>>(wq, wk, wv, wo, w1, w2, w3, wbt);
  k_prepcw<<<768, 256, 0, stream>>>(pw, wct);

  const _Float16* wt[3][7];
  for (int l = 0; l < 3; l++)
    for (int w = 0; w < 7; w++) wt[l][w] = wbt + (size_t)(l * 7 + w) * 16384;

  // layer 0 QKV
  k_qkv<<<512, 256, 0, stream>>>(h, wt[0][0], wt[0][1], wt[0][2], q, hk, hv);
  for (int l = 0; l < 3; l++) {
    const float* wk_l = wk + (size_t)l * 157 * 128;
    const float* wv_l = wv + (size_t)l * 157 * 128;
    k_attn<<<1024, 256, 0, stream>>>(q, hk, hv, nbr, edge,
                                     wk_l + 128 * 128, wv_l + 128 * 128, o);
    int nl = l + 1;
    int do_qkv = (nl < 3) ? 1 : 0;
    k_post<<<512, 256, 0, stream>>>(o, h, wt[l][3],
                                    wt[l][4], b1 + l * 128,
                                    wt[l][5], b2 + l * 128,
                                    wt[l][6], b3 + l * 128,
                                    do_qkv ? wt[nl][0] : nullptr,
                                    do_qkv ? wt[nl][1] : nullptr,
                                    do_qkv ? wt[nl][2] : nullptr,
                                    q, hk, hv, do_qkv);
  }

  k_convpool_m<<<dim3(8, 64), 256, 0, stream>>>(h,  wct + 0 * 49152, pb + 0,   xa, 512);
  k_convpool_m<<<dim3(4, 64), 256, 0, stream>>>(xa, wct + 1 * 49152, pb + 128, xb, 256);
  k_convpool_m<<<dim3(2, 64), 256, 0, stream>>>(xb, wct + 2 * 49152, pb + 256, xa, 128);
  k_convpool_m<<<dim3(1, 64), 256, 0, stream>>>(xa, wct + 3 * 49152, pb + 384, xb, 64);
  k_final<<<64, 128, 0, stream>>>(xb, ew, eb, outp);
}

// Round 6
// 567.688 us; speedup vs baseline: 2.8262x; 1.1369x over previous
//
#include <hip/hip_runtime.h>
#include <math.h>

#define N_TOT 32768
#define NNBR 15
#define EDGEF 29
#define APW 8

typedef __attribute__((ext_vector_type(8))) _Float16 f16x8;
typedef __attribute__((ext_vector_type(2))) _Float16 f16x2;
typedef __attribute__((ext_vector_type(4))) float f32x4;

#define CBAR() __asm__ volatile("" ::: "memory")

__device__ __forceinline__ _Float16 f2h(float x) { return (_Float16)x; }

// ---------------------------------------------------------------- frames
__global__ __launch_bounds__(256) void k_frames(const float* __restrict__ tert,
                                                float* __restrict__ pos,
                                                float* __restrict__ R) {
  int n = blockIdx.x * 256 + threadIdx.x;
  if (n >= N_TOT) return;
  float px = tert[n * 9 + 3], py = tert[n * 9 + 4], pz = tert[n * 9 + 5];
  pos[n * 3 + 0] = px; pos[n * 3 + 1] = py; pos[n * 3 + 2] = pz;

  int i0 = (n > 0) ? (n - 1) : 0;
  int i1 = (n < N_TOT - 1) ? n : (N_TOT - 2);

  float ax = tert[(i0 + 1) * 9 + 3] - tert[i0 * 9 + 3];
  float ay = tert[(i0 + 1) * 9 + 4] - tert[i0 * 9 + 4];
  float az = tert[(i0 + 1) * 9 + 5] - tert[i0 * 9 + 5];
  float il = 1.f / (sqrtf(ax * ax + ay * ay + az * az) + 1e-8f);
  float ux = ax * il, uy = ay * il, uz = az * il;

  float cx = tert[(i1 + 1) * 9 + 3] - tert[i1 * 9 + 3];
  float cy = tert[(i1 + 1) * 9 + 4] - tert[i1 * 9 + 4];
  float cz = tert[(i1 + 1) * 9 + 5] - tert[i1 * 9 + 5];
  il = 1.f / (sqrtf(cx * cx + cy * cy + cz * cz) + 1e-8f);
  float vx = cx * il, vy = cy * il, vz = cz * il;

  float bx = ux - vx, by = uy - vy, bz = uz - vz;
  il = 1.f / (sqrtf(bx * bx + by * by + bz * bz) + 1e-8f);
  bx *= il; by *= il; bz *= il;

  float nx = uy * vz - uz * vy;
  float ny = uz * vx - ux * vz;
  float nz = ux * vy - uy * vx;
  il = 1.f / (sqrtf(nx * nx + ny * ny + nz * nz) + 1e-8f);
  nx *= il; ny *= il; nz *= il;

  float ex = by * nz - bz * ny;
  float ey = bz * nx - bx * nz;
  float ez = bx * ny - by * nx;

  float* Rn = R + (size_t)n * 9;
  Rn[0] = bx; Rn[1] = nx; Rn[2] = ex;
  Rn[3] = by; Rn[4] = ny; Rn[5] = ey;
  Rn[6] = bz; Rn[7] = nz; Rn[8] = ez;
}

// ---------------------------------------------------------------- kNN, packed 64-bit keys
__global__ __launch_bounds__(256) void k_knn(const float* __restrict__ pos,
                                             const float* __restrict__ noise,
                                             int* __restrict__ nbr) {
  int wave = threadIdx.x >> 6, lane = threadIdx.x & 63;
  int row = blockIdx.x * 4 + wave;
  int b = row >> 9;
  float pix = pos[row * 3 + 0], piy = pos[row * 3 + 1], piz = pos[row * 3 + 2];
  const float* nrow = noise + (size_t)row * 512;
  const float* pb = pos + (size_t)b * 512 * 3;
  unsigned long long key[8];
#pragma unroll
  for (int jj = 0; jj < 8; jj++) {
    int j = lane + jj * 64;
    float dx = pb[j * 3 + 0] - pix;
    float dy = pb[j * 3 + 1] - piy;
    float dz = pb[j * 3 + 2] - piz;
    float c = -sqrtf(dx * dx + dy * dy + dz * dz) + 3.f * nrow[j];
    unsigned u = __float_as_uint(c);
    unsigned s = u ^ (unsigned)(((int)u >> 31) | (int)0x80000000);
    key[jj] = ((unsigned long long)s << 9) | (unsigned)(511 - j);
  }
  unsigned long long best = key[0];
#pragma unroll
  for (int jj = 1; jj < 8; jj++) best = key[jj] > best ? key[jj] : best;
  int jmine = 0;
#pragma unroll 1
  for (int it = 0; it < NNBR; it++) {
    unsigned long long g = best;
#pragma unroll
    for (int m = 1; m < 64; m <<= 1) {
      unsigned long long og = __shfl_xor(g, m);
      g = og > g ? og : g;
    }
    int j = 511 - (int)(g & 511ull);
    if (lane == it) jmine = j;
    if ((j & 63) == lane) {
      int slot = j >> 6;
#pragma unroll
      for (int jj = 0; jj < 8; jj++) if (slot == jj) key[jj] = 0ull;
      best = key[0];
#pragma unroll
      for (int jj = 1; jj < 8; jj++) best = key[jj] > best ? key[jj] : best;
    }
  }
  if (lane < NNBR) nbr[(size_t)row * NNBR + lane] = b * 512 + jmine;
}

// ---------------------------------------------------------------- edge features (fp16 out)
__global__ __launch_bounds__(256) void k_edge(const float* __restrict__ pos,
                                              const float* __restrict__ R,
                                              const int* __restrict__ nbr,
                                              _Float16* __restrict__ edge) {
  int idx = blockIdx.x * 256 + threadIdx.x;
  if (idx >= N_TOT * NNBR) return;
  int n = idx / NNBR;
  int m = nbr[idx];
  float dx = pos[m * 3 + 0] - pos[n * 3 + 0];
  float dy = pos[m * 3 + 1] - pos[n * 3 + 1];
  float dz = pos[m * 3 + 2] - pos[n * 3 + 2];
  float d = sqrtf(dx * dx + dy * dy + dz * dz);
  _Float16* e = edge + (size_t)idx * EDGEF;
#pragma unroll
  for (int j = 0; j < 16; j++) {
    float mu = (20.f / 15.f) * (float)j;
    float t = (d - mu) * 0.8f;
    e[j] = f2h(__expf(-t * t));
  }
  float inv = 1.f / (d + 1e-8f);
  float ux = dx * inv, uy = dy * inv, uz = dz * inv;
  float Rn[9], Rm[9];
#pragma unroll
  for (int j = 0; j < 9; j++) { Rn[j] = R[(size_t)n * 9 + j]; Rm[j] = R[(size_t)m * 9 + j]; }
#pragma unroll
  for (int cc = 0; cc < 3; cc++)
    e[16 + cc] = f2h(Rn[0 * 3 + cc] * ux + Rn[1 * 3 + cc] * uy + Rn[2 * 3 + cc] * uz);
#pragma unroll
  for (int cc = 0; cc < 3; cc++)
#pragma unroll
    for (int dd = 0; dd < 3; dd++)
      e[19 + cc * 3 + dd] = f2h(Rn[0 * 3 + cc] * Rm[0 * 3 + dd] +
                                Rn[1 * 3 + cc] * Rm[1 * 3 + dd] +
                                Rn[2 * 3 + cc] * Rm[2 * 3 + dd]);
  e[28] = f2h((float)(m - n));
}

// ---------------------------------------------------------------- h init (fp16)
__global__ __launch_bounds__(256) void k_hinit(const float* __restrict__ ew,
                                               const float* __restrict__ ebias,
                                               _Float16* __restrict__ h) {
  __shared__ float hv[128];
  int tid = threadIdx.x;
  if (tid < 128) {
    float s = ebias[tid];
#pragma unroll
    for (int i = 0; i < 27; i++) s += ew[i * 128 + tid];
    hv[tid] = s;
  }
  __syncthreads();
  size_t total = (size_t)N_TOT * 128;
  for (size_t j = (size_t)blockIdx.x * 256 + tid; j < total; j += (size_t)gridDim.x * 256)
    h[j] = f2h(hv[j & 127]);
}

// ---------------------------------------------------------------- dense weight prep: fp32 [k][n] -> fp16 [n][k]
__global__ __launch_bounds__(256) void k_prepw(const float* __restrict__ wq, const float* __restrict__ wk,
                                               const float* __restrict__ wv, const float* __restrict__ wo,
                                               const float* __restrict__ w1, const float* __restrict__ w2,
                                               const float* __restrict__ w3, _Float16* __restrict__ wbt) {
  int idx = blockIdx.x * 256 + threadIdx.x;
  if (idx >= 3 * 7 * 16384) return;
  int l = idx / (7 * 16384);
  int r = idx % (7 * 16384);
  int w = r / 16384;
  int e = r % 16384;
  int k = e >> 7, n = e & 127;
  float val;
  switch (w) {
    case 0: val = wq[(size_t)l * 16384 + e]; break;
    case 1: val = wk[(size_t)l * 157 * 128 + e]; break;
    case 2: val = wv[(size_t)l * 157 * 128 + e]; break;
    case 3: val = wo[(size_t)l * 16384 + e]; break;
    case 4: val = w1[(size_t)l * 16384 + e]; break;
    case 5: val = w2[(size_t)l * 16384 + e]; break;
    default: val = w3[(size_t)l * 16384 + e]; break;
  }
  wbt[(size_t)(l * 7 + w) * 16384 + n * 128 + k] = f2h(val);
}

// ---------------------------------------------------------------- Wqk composite: h -> qwk directly
// Wqk[c][j=e*8+hh] = 0.25 * sum_d Wq[c, hh*16+d] * Wk_e[e, hh*16+d]
// layout [l][blk][jp(row)][c(inner)] fp16 for stage_w
__global__ __launch_bounds__(256) void k_prepqk(const float* __restrict__ wq,
                                                const float* __restrict__ wk,
                                                _Float16* __restrict__ wqk) {
  int idx = blockIdx.x * 256 + threadIdx.x;
  if (idx >= 3 * 2 * 16384) return;
  int l = idx / 32768;
  int r = idx % 32768;
  int blk = r >> 14;
  int jp = (r >> 7) & 127;
  int c = r & 127;
  int j = blk * 128 + jp;
  float val = 0.f;
  if (j < 232) {
    int e = j >> 3, hh = j & 7;
    const float* wqp = wq + (size_t)l * 16384 + (size_t)c * 128 + hh * 16;
    const float* wkp = wk + (size_t)l * 157 * 128 + (size_t)(128 + e) * 128 + hh * 16;
    float s = 0.f;
#pragma unroll
    for (int d = 0; d < 16; d++) s = fmaf(wqp[d], wkp[d], s);
    val = 0.25f * s;
  }
  wqk[(size_t)idx] = f2h(val);
}

// ---------------------------------------------------------------- wpe = Wv_e'' @ Wo : [l][blk][cout][j'] fp16
__global__ __launch_bounds__(256) void k_preppe(const float* __restrict__ wv, const float* __restrict__ wo,
                                                _Float16* __restrict__ wpe) {
  int idx = blockIdx.x * 256 + threadIdx.x;
  if (idx >= 3 * 2 * 16384) return;
  int l = idx / 32768;
  int r = idx % 32768;
  int blk = r >> 14;
  int cout = (r >> 7) & 127;
  int jp = r & 127;
  int j = blk * 128 + jp;
  float val = 0.f;
  if (j < 232) {
    int e = j >> 3, hh = j & 7;
    const float* wvp = wv + (size_t)l * 157 * 128 + (size_t)(128 + e) * 128 + hh * 16;
    const float* wop = wo + (size_t)l * 16384 + (size_t)(hh * 16) * 128 + cout;
#pragma unroll
    for (int d = 0; d < 16; d++) val = fmaf(wvp[d], wop[d * 128], val);
  }
  wpe[(size_t)idx] = f2h(val);
}

// ---------------------------------------------------------------- conv weight prep
__global__ __launch_bounds__(256) void k_prepcw(const float* __restrict__ pw, _Float16* __restrict__ wc) {
  int idx = blockIdx.x * 256 + threadIdx.x;
  if (idx >= 4 * 128 * 128 * 3) return;
  int kt = idx % 3;
  int rest = idx / 3;
  int i = rest % 128; rest /= 128;
  int oo = rest % 128;
  int s = rest / 128;
  wc[(((size_t)s * 3 + kt) * 128 + oo) * 128 + i] = f2h(pw[idx]);
}

// ---------------------------------------------------------------- shared GEMM helpers
__device__ __forceinline__ void stage_w(const _Float16* __restrict__ W, _Float16* Ws, int tid) {
  for (int j = tid; j < 2048; j += 256) {
    int row = j >> 4, seg = (j & 15) * 8;
    *(uint4*)&Ws[row * 136 + seg] = *(const uint4*)(W + (size_t)row * 128 + seg);
  }
}
template <bool RESET>
__device__ __forceinline__ void gemm_tile_t(const _Float16* X, const _Float16* Ws,
                                            int wrow, int l16, int quad, f32x4 acc[8]) {
  if (RESET) {
#pragma unroll
    for (int t = 0; t < 8; t++) acc[t] = (f32x4){0.f, 0.f, 0.f, 0.f};
  }
#pragma unroll
  for (int kk = 0; kk < 4; kk++) {
    f16x8 a = *(const f16x8*)&X[(wrow + l16) * 136 + kk * 32 + quad * 8];
#pragma unroll
    for (int t = 0; t < 8; t++) {
      f16x8 b = *(const f16x8*)&Ws[(t * 16 + l16) * 136 + kk * 32 + quad * 8];
      acc[t] = __builtin_amdgcn_mfma_f32_16x16x32_f16(a, b, acc[t], 0, 0, 0);
    }
  }
}

// ---------------------------------------------------------------- layer-0 QKV (+qwk via composite)
__global__ __launch_bounds__(256) void k_qkv(const _Float16* __restrict__ A,
                                             const _Float16* __restrict__ Wqt,
                                             const _Float16* __restrict__ Wkt,
                                             const _Float16* __restrict__ Wvt,
                                             const _Float16* __restrict__ Wqk0,
                                             const _Float16* __restrict__ Wqk1,
                                             _Float16* __restrict__ q, _Float16* __restrict__ hk,
                                             _Float16* __restrict__ hv, _Float16* __restrict__ qkw) {
  __shared__ _Float16 X[64 * 136];
  __shared__ _Float16 Ws[128 * 136];
  int tid = threadIdx.x, r0 = blockIdx.x * 64;
  int lane = tid & 63, quad = lane >> 4, l16 = lane & 15, wrow = (tid >> 6) * 16;
  for (int j = tid; j < 1024; j += 256) {
    int row = j >> 4, seg = (j & 15) * 8;
    *(uint4*)&X[row * 136 + seg] = *(const uint4*)(A + (size_t)(r0 + row) * 128 + seg);
  }
  const _Float16* wts[5] = {Wqt, Wkt, Wvt, Wqk0, Wqk1};
  f32x4 acc[8];
  for (int w = 0; w < 5; w++) {
    __syncthreads();
    stage_w(wts[w], Ws, tid);
    __syncthreads();
    gemm_tile_t<true>(X, Ws, wrow, l16, quad, acc);
#pragma unroll
    for (int t = 0; t < 8; t++) {
      int col = t * 16 + l16;
#pragma unroll
      for (int r = 0; r < 4; r++) {
        float v = acc[t][r];
        int rowg = r0 + wrow + quad * 4 + r;
        if (w < 3) {
          _Float16* C = (w == 0) ? q : (w == 1) ? hk : hv;
          C[(size_t)rowg * 128 + col] = f2h(v);
        } else {
          qkw[(size_t)rowg * 256 + (w - 3) * 128 + col] = f2h(v);
        }
      }
    }
  }
}

// ---------------------------------------------------------------- fused o-proj(+pe) + residual + MLP (+ next QKV+qwk)
__global__ __launch_bounds__(256) void k_post(const _Float16* __restrict__ o,
                                              const _Float16* __restrict__ pe_g,
                                              _Float16* __restrict__ h,
                                              const _Float16* __restrict__ Wot,
                                              const _Float16* __restrict__ Wpe0,
                                              const _Float16* __restrict__ Wpe1,
                                              const _Float16* __restrict__ W1t, const float* __restrict__ B1,
                                              const _Float16* __restrict__ W2t, const float* __restrict__ B2,
                                              const _Float16* __restrict__ W3t, const float* __restrict__ B3,
                                              const _Float16* __restrict__ Wqt,
                                              const _Float16* __restrict__ Wkt,
                                              const _Float16* __restrict__ Wvt,
                                              const _Float16* __restrict__ Wqk0,
                                              const _Float16* __restrict__ Wqk1,
                                              _Float16* __restrict__ qo, _Float16* __restrict__ hko,
                                              _Float16* __restrict__ hvo, _Float16* __restrict__ qkwo,
                                              int do_qkv) {
  __shared__ _Float16 X[64 * 136];
  __shared__ _Float16 Ws[128 * 136];
  int tid = threadIdx.x, r0 = blockIdx.x * 64;
  int lane = tid & 63, quad = lane >> 4, l16 = lane & 15, wrow = (tid >> 6) * 16;
  for (int j = tid; j < 1024; j += 256) {
    int row = j >> 4, seg = (j & 15) * 8;
    *(uint4*)&X[row * 136 + seg] = *(const uint4*)(o + (size_t)(r0 + row) * 128 + seg);
  }
  stage_w(Wot, Ws, tid);
  __syncthreads();
  f32x4 acc[8], hres[8];
  gemm_tile_t<true>(X, Ws, wrow, l16, quad, acc);
  // accumulate pe @ Wpe (two 128-k chunks)
  const _Float16* wpes[2] = {Wpe0, Wpe1};
#pragma unroll 1
  for (int blk = 0; blk < 2; blk++) {
    __syncthreads();
    for (int j = tid; j < 1024; j += 256) {
      int row = j >> 4, seg = (j & 15) * 8;
      *(uint4*)&X[row * 136 + seg] = *(const uint4*)(pe_g + (size_t)(r0 + row) * 256 + blk * 128 + seg);
    }
    stage_w(wpes[blk], Ws, tid);
    __syncthreads();
    gemm_tile_t<false>(X, Ws, wrow, l16, quad, acc);
  }
#pragma unroll
  for (int t = 0; t < 8; t++) {
    int col = t * 16 + l16;
#pragma unroll
    for (int r = 0; r < 4; r++)
      hres[t][r] = acc[t][r] + (float)h[(size_t)(r0 + wrow + quad * 4 + r) * 128 + col];
  }
  __syncthreads();
#pragma unroll
  for (int t = 0; t < 8; t++) {
    int col = t * 16 + l16;
#pragma unroll
    for (int r = 0; r < 4; r++)
      X[(wrow + quad * 4 + r) * 136 + col] = f2h(hres[t][r]);
  }
  stage_w(W1t, Ws, tid);
  __syncthreads();
  gemm_tile_t<true>(X, Ws, wrow, l16, quad, acc);
  __syncthreads();
#pragma unroll
  for (int t = 0; t < 8; t++) {
    int col = t * 16 + l16; float bv = B1[col];
#pragma unroll
    for (int r = 0; r < 4; r++)
      X[(wrow + quad * 4 + r) * 136 + col] = f2h(fmaxf(acc[t][r] + bv, 0.f));
  }
  stage_w(W2t, Ws, tid);
  __syncthreads();
  gemm_tile_t<true>(X, Ws, wrow, l16, quad, acc);
  __syncthreads();
#pragma unroll
  for (int t = 0; t < 8; t++) {
    int col = t * 16 + l16; float bv = B2[col];
#pragma unroll
    for (int r = 0; r < 4; r++)
      X[(wrow + quad * 4 + r) * 136 + col] = f2h(fmaxf(acc[t][r] + bv, 0.f));
  }
  stage_w(W3t, Ws, tid);
  __syncthreads();
  gemm_tile_t<true>(X, Ws, wrow, l16, quad, acc);
  __syncthreads();
#pragma unroll
  for (int t = 0; t < 8; t++) {
    int col = t * 16 + l16; float bv = B3[col];
#pragma unroll
    for (int r = 0; r < 4; r++) {
      float v = hres[t][r] + acc[t][r] + bv;
      h[(size_t)(r0 + wrow + quad * 4 + r) * 128 + col] = f2h(v);
      if (do_qkv) X[(wrow + quad * 4 + r) * 136 + col] = f2h(v);
    }
  }
  if (!do_qkv) return;
  const _Float16* wts[5] = {Wqt, Wkt, Wvt, Wqk0, Wqk1};
  for (int w = 0; w < 5; w++) {
    __syncthreads();
    stage_w(wts[w], Ws, tid);
    __syncthreads();
    gemm_tile_t<true>(X, Ws, wrow, l16, quad, acc);
#pragma unroll
    for (int t = 0; t < 8; t++) {
      int col = t * 16 + l16;
#pragma unroll
      for (int r = 0; r < 4; r++) {
        float v = acc[t][r];
        int rowg = r0 + wrow + quad * 4 + r;
        if (w < 3) {
          _Float16* C = (w == 0) ? qo : (w == 1) ? hko : hvo;
          C[(size_t)rowg * 128 + col] = f2h(v);
        } else {
          qkwo[(size_t)rowg * 256 + (w - 3) * 128 + col] = f2h(v);
        }
      }
    }
  }
}

// ---------------------------------------------------------------- attention core (gather + softmax + pe)
__global__ __launch_bounds__(256) void k_attn(const _Float16* __restrict__ q,
                                              const _Float16* __restrict__ hk,
                                              const _Float16* __restrict__ hv,
                                              const int* __restrict__ nbr,
                                              const _Float16* __restrict__ edge,
                                              const _Float16* __restrict__ qkw,
                                              _Float16* __restrict__ o,
                                              _Float16* __restrict__ pe_g) {
  __shared__ float eL[4][15 * 33];
  __shared__ float qwkL[4][232];
  __shared__ float pL[4][120];
  __shared__ int nbrL[4][16];
  int tid = threadIdx.x, wave = tid >> 6, lane = tid & 63;
  float* el = eL[wave];
  float* qwk = qwkL[wave];
  float* pl = pL[wave];
  int* nbl = nbrL[wave];
  int h8 = lane & 7, k2 = lane >> 3, c2 = lane * 2, h5 = lane >> 3;
  int n0 = (blockIdx.x * 4 + wave) * APW;
#pragma unroll 1
  for (int ni = 0; ni < APW; ni++) {
    int n = n0 + ni;
    // P0: stage edge (fp16->fp32), qwk, nbr
    const _Float16* es = edge + (size_t)n * 435;
#pragma unroll
    for (int jj = 0; jj < 7; jj++) {
      int j = lane + jj * 64;
      if (j < 435) el[(j / 29) * 33 + (j % 29)] = (float)es[j];
    }
    const _Float16* qs = qkw + (size_t)n * 256;
#pragma unroll
    for (int jj = 0; jj < 4; jj++) {
      int j = lane + jj * 64;
      if (j < 232) qwk[j] = (float)qs[j];
    }
    if (lane < 15) nbl[lane] = nbr[(size_t)n * NNBR + lane];
    CBAR();
    // P1: logits (hk gathers + edge term)
    const _Float16* qp = q + (size_t)n * 128 + h8 * 16;
    f16x8 qa = *(const f16x8*)qp;
    f16x8 qb = *(const f16x8*)(qp + 8);
    float q16[16];
#pragma unroll
    for (int d = 0; d < 8; d++) { q16[d] = (float)qa[d]; q16[8 + d] = (float)qb[d]; }
#pragma unroll
    for (int p = 0; p < 2; p++) {
      int k = p * 8 + k2;
      if (k < 15) {
        int m = nbl[k];
        const _Float16* hkp = hk + (size_t)m * 128 + h8 * 16;
        f16x8 ha = *(const f16x8*)hkp;
        f16x8 hb = *(const f16x8*)(hkp + 8);
        float dot = 0.f;
#pragma unroll
        for (int d = 0; d < 8; d++) dot = fmaf(q16[d], (float)ha[d], dot);
#pragma unroll
        for (int d = 0; d < 8; d++) dot = fmaf(q16[8 + d], (float)hb[d], dot);
        float ep = 0.f;
#pragma unroll
        for (int e = 0; e < 29; e++) ep = fmaf(el[k * 33 + e], qwk[e * 8 + h8], ep);
        pl[k * 8 + h8] = 0.25f * dot + ep;
      }
    }
    CBAR();
    // P2: softmax per head
    if (lane < 8) {
      float mx = -1e30f;
#pragma unroll
      for (int k = 0; k < 15; k++) mx = fmaxf(mx, pl[k * 8 + lane]);
      float pv[15], s = 0.f;
#pragma unroll
      for (int k = 0; k < 15; k++) { pv[k] = __expf(pl[k * 8 + lane] - mx); s += pv[k]; }
      float inv = 1.f / s;
#pragma unroll
      for (int k = 0; k < 15; k++) pl[k * 8 + lane] = pv[k] * inv;
    }
    CBAR();
    // P3: pe[e][h] -> global (fp16), zero-pad 232..255
    _Float16* peo = pe_g + (size_t)n * 256;
#pragma unroll
    for (int p = 0; p < 4; p++) {
      int j = p * 64 + lane;
      float s = 0.f;
      if (j < 232) {
        int e = j >> 3;
#pragma unroll
        for (int k = 0; k < 15; k++) s = fmaf(pl[k * 8 + h8], el[k * 33 + e], s);
      }
      peo[j] = f2h(s);
    }
    // P4: o_node channels
    float ox = 0.f, oy = 0.f;
#pragma unroll
    for (int k = 0; k < 15; k++) {
      int m = nbl[k];
      f16x2 hh = *(const f16x2*)(hv + (size_t)m * 128 + c2);
      float pk = pl[k * 8 + h5];
      ox = fmaf(pk, (float)hh.x, ox);
      oy = fmaf(pk, (float)hh.y, oy);
    }
    f16x2 o2 = {f2h(ox), f2h(oy)};
    *(f16x2*)(o + (size_t)n * 128 + c2) = o2;
    CBAR();
  }
}

// ---------------------------------------------------------------- MFMA conv+leaky+residual+maxpool2 (fp16 I/O)
__global__ __launch_bounds__(256) void k_convpool_m(const _Float16* __restrict__ x,
                                                    const _Float16* __restrict__ Wc,
                                                    const float* __restrict__ bias,
                                                    _Float16* __restrict__ outp, int Tin) {
  __shared__ _Float16 Xs[66 * 136];
  __shared__ _Float16 Ws[128 * 136];
  int tid = threadIdx.x;
  int b = blockIdx.y;
  int t0 = blockIdx.x * 64;
  for (int j = tid; j < 66 * 16; j += 256) {
    int row = j >> 4, seg = (j & 15) * 8;
    int t = t0 - 1 + row;
    uint4 v = {0u, 0u, 0u, 0u};
    if (t >= 0 && t < Tin) v = *(const uint4*)(x + ((size_t)b * Tin + t) * 128 + seg);
    *(uint4*)&Xs[row * 136 + seg] = v;
  }
  int lane = tid & 63, quad = lane >> 4, l16 = lane & 15, wrow = (tid >> 6) * 16;
  f32x4 acc[8];
#pragma unroll
  for (int t = 0; t < 8; t++) acc[t] = (f32x4){0.f, 0.f, 0.f, 0.f};
  for (int kt = 0; kt < 3; kt++) {
    __syncthreads();
    stage_w(Wc + (size_t)kt * 16384, Ws, tid);
    __syncthreads();
#pragma unroll
    for (int kk = 0; kk < 4; kk++) {
      f16x8 a = *(const f16x8*)&Xs[(wrow + l16 + kt) * 136 + kk * 32 + quad * 8];
#pragma unroll
      for (int t = 0; t < 8; t++) {
        f16x8 bfr = *(const f16x8*)&Ws[(t * 16 + l16) * 136 + kk * 32 + quad * 8];
        acc[t] = __builtin_amdgcn_mfma_f32_16x16x32_f16(a, bfr, acc[t], 0, 0, 0);
      }
    }
  }
  int Tout = Tin >> 1;
#pragma unroll
  for (int t = 0; t < 8; t++) {
    int col = t * 16 + l16;
    float bv = bias[col];
#pragma unroll
    for (int rp = 0; rp < 2; rp++) {
      int rl0 = wrow + quad * 4 + rp * 2;
      float y0 = acc[t][rp * 2] + bv;
      float y1 = acc[t][rp * 2 + 1] + bv;
      float z0 = (float)Xs[(rl0 + 1) * 136 + col] + (y0 >= 0.f ? y0 : 0.01f * y0);
      float z1 = (float)Xs[(rl0 + 2) * 136 + col] + (y1 >= 0.f ? y1 : 0.01f * y1);
      outp[((size_t)b * Tout + ((t0 + rl0) >> 1)) * 128 + col] = f2h(fmaxf(z0, z1));
    }
  }
}

// ---------------------------------------------------------------- final reduce
__global__ __launch_bounds__(128) void k_final(const _Float16* __restrict__ x,
                                               const float* __restrict__ ew,
                                               const float* __restrict__ ebb,
                                               float* __restrict__ outp) {
  int b = blockIdx.x, cc = threadIdx.x;
  float s = 0.f;
#pragma unroll
  for (int t = 0; t < 32; t++) s += (float)x[((size_t)b * 32 + t) * 128 + cc];
  float v = s * ew[cc];
#pragma unroll
  for (int m = 1; m < 64; m <<= 1) v += __shfl_xor(v, m);
  __shared__ float red[2];
  if ((cc & 63) == 0) red[cc >> 6] = v;
  __syncthreads();
  if (cc == 0) outp[b] = red[0] + red[1] + ebb[0];
}

// ---------------------------------------------------------------- launch
extern "C" void kernel_launch(void* const* d_in, const int* in_sizes, int n_in,
                              void* d_out, int out_size, void* d_ws, size_t ws_size,
                              hipStream_t stream) {
  (void)in_sizes; (void)n_in; (void)out_size; (void)ws_size;
  const float* tert    = (const float*)d_in[0];
  const float* noise   = (const float*)d_in[3];
  const float* embed_w = (const float*)d_in[4];
  const float* embed_b = (const float*)d_in[5];
  const float* wq = (const float*)d_in[6];
  const float* wk = (const float*)d_in[7];
  const float* wv = (const float*)d_in[8];
  const float* wo = (const float*)d_in[9];
  const float* w1 = (const float*)d_in[10];
  const float* b1 = (const float*)d_in[11];
  const float* w2 = (const float*)d_in[12];
  const float* b2 = (const float*)d_in[13];
  const float* w3 = (const float*)d_in[14];
  const float* b3 = (const float*)d_in[15];
  const float* pw = (const float*)d_in[16];
  const float* pb = (const float*)d_in[17];
  const float* ew = (const float*)d_in[18];
  const float* eb = (const float*)d_in[19];
  float* outp = (float*)d_out;

  char* W = (char*)d_ws;
  float* pos  = (float*)W;        W += 393216;     // N*3 f32
  float* R    = (float*)W;        W += 1179648;    // N*9 f32
  int*   nbr  = (int*)W;          W += 1966080;    // N*15 i32
  _Float16* edge = (_Float16*)W;  W += 28508160;   // N*435 f16
  _Float16* h    = (_Float16*)W;  W += 8388608;    // N*128 f16
  _Float16* q    = (_Float16*)W;  W += 8388608;
  _Float16* hk   = (_Float16*)W;  W += 8388608;
  _Float16* hv   = (_Float16*)W;  W += 8388608;
  _Float16* o    = (_Float16*)W;  W += 8388608;
  _Float16* qkw_g = (_Float16*)W; W += 16777216;   // N*256 f16
  _Float16* pe_g  = (_Float16*)W; W += 16777216;   // N*256 f16
  _Float16* xa   = (_Float16*)W;  W += 4194304;    // B*256*128 f16
  _Float16* xb   = (_Float16*)W;  W += 2097152;    // B*128*128 f16
  _Float16* wbt  = (_Float16*)W;  W += 688128;     // 21*16384 f16
  _Float16* wqk  = (_Float16*)W;  W += 196608;     // 3*2*16384 f16
  _Float16* wpe  = (_Float16*)W;  W += 196608;     // 3*2*16384 f16
  _Float16* wct  = (_Float16*)W;  W += 393216;     // 12*16384 f16

  k_frames<<<128, 256, 0, stream>>>(tert, pos, R);
  k_knn<<<8192, 256, 0, stream>>>(pos, noise, nbr);
  k_edge<<<1920, 256, 0, stream>>>(pos, R, nbr, edge);
  k_hinit<<<512, 256, 0, stream>>>(embed_w, embed_b, h);
  k_prepw<<<1344, 256, 0, stream>>>(wq, wk, wv, wo, w1, w2, w3, wbt);
  k_prepqk<<<384, 256, 0, stream>>>(wq, wk, wqk);
  k_preppe<<<384, 256, 0, stream>>>(wv, wo, wpe);
  k_prepcw<<<768, 256, 0, stream>>>(pw, wct);

  const _Float16* wt[3][7];
  for (int l = 0; l < 3; l++)
    for (int w = 0; w < 7; w++) wt[l][w] = wbt + (size_t)(l * 7 + w) * 16384;
  const _Float16* wqk_l[3][2];
  const _Float16* wpe_l[3][2];
  for (int l = 0; l < 3; l++)
    for (int bk = 0; bk < 2; bk++) {
      wqk_l[l][bk] = wqk + (size_t)(l * 2 + bk) * 16384;
      wpe_l[l][bk] = wpe + (size_t)(l * 2 + bk) * 16384;
    }

  k_qkv<<<512, 256, 0, stream>>>(h, wt[0][0], wt[0][1], wt[0][2],
                                 wqk_l[0][0], wqk_l[0][1], q, hk, hv, qkw_g);
  for (int l = 0; l < 3; l++) {
    k_attn<<<1024, 256, 0, stream>>>(q, hk, hv, nbr, edge, qkw_g, o, pe_g);
    int nl = l + 1;
    int do_qkv = (nl < 3) ? 1 : 0;
    k_post<<<512, 256, 0, stream>>>(o, pe_g, h, wt[l][3],
                                    wpe_l[l][0], wpe_l[l][1],
                                    wt[l][4], b1 + l * 128,
                                    wt[l][5], b2 + l * 128,
                                    wt[l][6], b3 + l * 128,
                                    do_qkv ? wt[nl][0] : nullptr,
                                    do_qkv ? wt[nl][1] : nullptr,
                                    do_qkv ? wt[nl][2] : nullptr,
                                    do_qkv ? wqk_l[nl][0] : nullptr,
                                    do_qkv ? wqk_l[nl][1] : nullptr,
                                    q, hk, hv, qkw_g, do_qkv);
  }

  k_convpool_m<<<dim3(8, 64), 256, 0, stream>>>(h,  wct + 0 * 49152, pb + 0,   xa, 512);
  k_convpool_m<<<dim3(4, 64), 256, 0, stream>>>(xa, wct + 1 * 49152, pb + 128, xb, 256);
  k_convpool_m<<<dim3(2, 64), 256, 0, stream>>>(xb, wct + 2 * 49152, pb + 256, xa, 128);
  k_convpool_m<<<dim3(1, 64), 256, 0, stream>>>(xa, wct + 3 * 49152, pb + 384, xb, 64);
  k_final<<<64, 128, 0, stream>>>(xb, ew, eb, outp);
}